// Round 1
// baseline (7295.412 us; speedup 1.0000x reference)
//
#include <hip/hip_runtime.h>
#include <hip/hip_bf16.h>
#include <math.h>

#define BB 32
#define CC 64
#define C2 32
#define HH 32
#define WW 32
#define HW 1024
#define NTOT 3278
#define NPAD 3280
#define CBATCH 4
#define KT 32

__device__ __constant__ int SC_SIZE[5] = {32, 28, 25, 22, 19};
__device__ __constant__ int SC_OFF[6]  = {0, 1024, 1808, 2433, 2917, 3278};

// ---------------- stage A: match_base = PReLU(conv1x1(x, w_base)) ----------------
__global__ void k_match_base(const float* __restrict__ x, const float* __restrict__ w,
                             const float* __restrict__ bias, const float* __restrict__ a,
                             float* __restrict__ mb) {
    int t = blockIdx.x * blockDim.x + threadIdx.x;   // t in [0, B*HW)
    int b = t >> 10, p = t & 1023;
    float alpha = a[0];
    float xv[CC];
    const float* xb = x + (size_t)b * CC * HW + p;
#pragma unroll
    for (int c = 0; c < CC; ++c) xv[c] = xb[c * HW];
    for (int o = 0; o < C2; ++o) {
        float acc = bias[o];
#pragma unroll
        for (int c = 0; c < CC; ++c) acc += w[o * CC + c] * xv[c];
        mb[((size_t)b * C2 + o) * HW + p] = acc >= 0.f ? acc : alpha * acc;
    }
}

// ---------------- stage B: per-scale refm/base features (concatenated over scales) ----------------
__global__ void k_scale_feats(const float* __restrict__ x,
                              const float* __restrict__ wm, const float* __restrict__ bm, const float* __restrict__ am,
                              const float* __restrict__ wa, const float* __restrict__ ba, const float* __restrict__ aa,
                              float* __restrict__ refm, float* __restrict__ base) {
    int t = blockIdx.x * blockDim.x + threadIdx.x;
    if (t >= BB * NTOT) return;
    int b = t / NTOT, n = t % NTOT;
    int s = 0;
    while (s < 4 && n >= SC_OFF[s + 1]) ++s;
    int q = n - SC_OFF[s];
    int hs = SC_SIZE[s];
    int ny = q / hs, nx = q % hs;
    int iy = (ny * HH) / hs, ix = (nx * WW) / hs;
    const float* xb = x + (size_t)b * CC * HW + iy * WW + ix;
    float xv[CC];
#pragma unroll
    for (int c = 0; c < CC; ++c) xv[c] = xb[c * HW];
    float alm = am[0], ala = aa[0];
    for (int o = 0; o < CC; ++o) {
        float acc = ba[o];
#pragma unroll
        for (int c = 0; c < CC; ++c) acc += wa[o * CC + c] * xv[c];
        base[((size_t)b * CC + o) * NTOT + n] = acc >= 0.f ? acc : ala * acc;
    }
    for (int o = 0; o < C2; ++o) {
        float acc = bm[o];
#pragma unroll
        for (int c = 0; c < CC; ++c) acc += wm[o * CC + c] * xv[c];
        refm[((size_t)b * C2 + o) * NTOT + n] = acc >= 0.f ? acc : alm * acc;
    }
}

// ---------------- neighbor table: nbr[kk][n] = concat-index of patch tap kk at n, or -1 ----------------
__global__ void k_nbr(int* __restrict__ nbr) {
    int n = blockIdx.x * blockDim.x + threadIdx.x;
    if (n >= NTOT) return;
    int s = 0;
    while (s < 4 && n >= SC_OFF[s + 1]) ++s;
    int q = n - SC_OFF[s];
    int hs = SC_SIZE[s];
    int ny = q / hs, nx = q % hs;
    for (int dy = 0; dy < 3; ++dy)
        for (int dx = 0; dx < 3; ++dx) {
            int yy = ny + dy - 1, xx = nx + dx - 1;
            int idx = (yy >= 0 && yy < hs && xx >= 0 && xx < hs) ? (SC_OFF[s] + yy * hs + xx) : -1;
            nbr[(dy * 3 + dx) * NTOT + n] = idx;
        }
}

// ---------------- per-(b,n) filter norms; sinv = softmax_scale / max(norm, 1e-4) ----------------
__global__ void k_norms(const float* __restrict__ refm, const int* __restrict__ nbr,
                        float* __restrict__ sinv) {
    int t = blockIdx.x * blockDim.x + threadIdx.x;
    if (t >= BB * NTOT) return;
    int b = t / NTOT, n = t % NTOT;
    float sum = 0.f;
    for (int kk = 0; kk < 9; ++kk) {
        int idx = nbr[kk * NTOT + n];
        if (idx < 0) continue;
        const float* r = refm + (size_t)b * C2 * NTOT + idx;
#pragma unroll
        for (int c = 0; c < C2; ++c) {
            float v = r[(size_t)c * NTOT];
            sum += v * v;
        }
    }
    sinv[t] = 10.0f / fmaxf(sqrtf(sum), 1e-4f);
}

// ---------------- correlation GEMM: yi[cb][p][n] = sinv[b][n] * sum_k xp[p,k]*wi[n,k] ----------------
__global__ void k_corr(const float* __restrict__ mb, const float* __restrict__ refm,
                       const int* __restrict__ nbr, const float* __restrict__ sinv,
                       float* __restrict__ yi, int b0) {
    int cb = blockIdx.z, b = b0 + cb;
    int p0 = blockIdx.x * 64, n0 = blockIdx.y * 64;
    int tid = threadIdx.x;
    int ty = tid >> 4, tx = tid & 15;
    __shared__ float As[KT][64];   // xp tile [k][p]
    __shared__ float Bs[KT][64];   // wi tile [k][n]
    float acc[4][4] = {};
    const float* mbb = mb + (size_t)b * C2 * HW;
    const float* rmb = refm + (size_t)b * C2 * NTOT;
    for (int k0 = 0; k0 < 288; k0 += KT) {
        // load xp tile: e = kt*64 + i  (consecutive threads -> consecutive p)
        for (int e = tid; e < KT * 64; e += 256) {
            int kt = e >> 6, i = e & 63;
            int k = k0 + kt;
            int c2 = k / 9, kk = k % 9;
            int p = p0 + i;
            int py = (p >> 5) + kk / 3 - 1;
            int px = (p & 31) + kk % 3 - 1;
            float v = 0.f;
            if (py >= 0 && py < HH && px >= 0 && px < WW)
                v = mbb[(size_t)c2 * HW + py * WW + px];
            As[kt][i] = v;
        }
        // load wi tile: e = kt*64 + j  (consecutive threads -> consecutive n)
        for (int e = tid; e < KT * 64; e += 256) {
            int kt = e >> 6, j = e & 63;
            int k = k0 + kt;
            int c2 = k / 9, kk = k % 9;
            int n = n0 + j;
            float v = 0.f;
            if (n < NTOT) {
                int idx = nbr[kk * NTOT + n];
                if (idx >= 0) v = rmb[(size_t)c2 * NTOT + idx];
            }
            Bs[kt][j] = v;
        }
        __syncthreads();
#pragma unroll 8
        for (int kt = 0; kt < KT; ++kt) {
            float av[4], bv[4];
#pragma unroll
            for (int ii = 0; ii < 4; ++ii) av[ii] = As[kt][ty * 4 + ii];
#pragma unroll
            for (int jj = 0; jj < 4; ++jj) bv[jj] = Bs[kt][tx * 4 + jj];
#pragma unroll
            for (int ii = 0; ii < 4; ++ii)
#pragma unroll
                for (int jj = 0; jj < 4; ++jj) acc[ii][jj] += av[ii] * bv[jj];
        }
        __syncthreads();
    }
#pragma unroll
    for (int ii = 0; ii < 4; ++ii) {
        int p = p0 + ty * 4 + ii;
#pragma unroll
        for (int jj = 0; jj < 4; ++jj) {
            int n = n0 + tx * 4 + jj;
            if (n < NTOT)
                yi[((size_t)cb * HW + p) * NPAD + n] = acc[ii][jj] * sinv[(size_t)b * NTOT + n];
        }
    }
}

// ---------------- softmax over n for each row (cb,p) ----------------
__global__ void k_softmax(float* __restrict__ yi) {
    float* r = yi + (size_t)blockIdx.x * NPAD;
    __shared__ float red[256];
    int tid = threadIdx.x;
    float m = -1e30f;
    for (int n = tid; n < NTOT; n += 256) m = fmaxf(m, r[n]);
    red[tid] = m;
    __syncthreads();
    for (int s = 128; s > 0; s >>= 1) {
        if (tid < s) red[tid] = fmaxf(red[tid], red[tid + s]);
        __syncthreads();
    }
    m = red[0];
    __syncthreads();
    float sum = 0.f;
    for (int n = tid; n < NTOT; n += 256) {
        float e = __expf(r[n] - m);
        r[n] = e;
        sum += e;
    }
    red[tid] = sum;
    __syncthreads();
    for (int s = 128; s > 0; s >>= 1) {
        if (tid < s) red[tid] += red[tid + s];
        __syncthreads();
    }
    float inv = 1.0f / red[0];
    for (int n = tid; n < NTOT; n += 256) r[n] *= inv;
}

// ---------------- fold GEMM: outacc[cb][m=(c*9+kk)][p] = sum_n V[m,n]*prob[p,n] ----------------
__global__ void k_fold(const float* __restrict__ base, const int* __restrict__ nbr,
                       const float* __restrict__ yi, float* __restrict__ outacc, int b0) {
    int cb = blockIdx.z, b = b0 + cb;
    int p0 = blockIdx.x * 64, m0 = blockIdx.y * 64;
    int tid = threadIdx.x;
    int ty = tid >> 4, tx = tid & 15;
    __shared__ float As[KT][65];   // V tile [n][m]
    __shared__ float Bs[KT][65];   // prob tile [n][p]
    float acc[4][4] = {};
    const float* bb = base + (size_t)b * CC * NTOT;
    for (int nk0 = 0; nk0 < NTOT; nk0 += KT) {
        // V: e = mi*32 + nt  (consecutive threads -> consecutive n: coalesced gather)
        for (int e = tid; e < 64 * KT; e += 256) {
            int mi = e >> 5, nt = e & 31;
            int m = m0 + mi;
            int c = m / 9, kk = m % 9;
            int n = nk0 + nt;
            float v = 0.f;
            if (n < NTOT) {
                int idx = nbr[kk * NTOT + n];
                if (idx >= 0) v = bb[(size_t)c * NTOT + idx];
            }
            As[nt][mi] = v;
        }
        // prob: e = pj*32 + nt  (consecutive threads -> consecutive n: contiguous)
        for (int e = tid; e < 64 * KT; e += 256) {
            int pj = e >> 5, nt = e & 31;
            int n = nk0 + nt;
            Bs[nt][pj] = (n < NTOT) ? yi[((size_t)cb * HW + p0 + pj) * NPAD + n] : 0.f;
        }
        __syncthreads();
#pragma unroll 8
        for (int nt = 0; nt < KT; ++nt) {
            float av[4], bv[4];
#pragma unroll
            for (int ii = 0; ii < 4; ++ii) av[ii] = As[nt][ty * 4 + ii];
#pragma unroll
            for (int jj = 0; jj < 4; ++jj) bv[jj] = Bs[nt][tx * 4 + jj];
#pragma unroll
            for (int ii = 0; ii < 4; ++ii)
#pragma unroll
                for (int jj = 0; jj < 4; ++jj) acc[ii][jj] += av[ii] * bv[jj];
        }
        __syncthreads();
    }
#pragma unroll
    for (int ii = 0; ii < 4; ++ii) {
        int m = m0 + ty * 4 + ii;
#pragma unroll
        for (int jj = 0; jj < 4; ++jj) {
            int p = p0 + tx * 4 + jj;
            outacc[((size_t)cb * 576 + m) * HW + p] = acc[ii][jj];
        }
    }
}

// ---------------- epilogue: out = x + 0.25 * sum_{ky,kx} outacc[(c,ky*3+kx)][y+1-ky, x+1-kx] ----------------
__global__ void k_epilogue(const float* __restrict__ x, const float* __restrict__ outacc,
                           float* __restrict__ out, int b0) {
    int t = blockIdx.x * blockDim.x + threadIdx.x;   // [0, CBATCH*C*HW)
    int cb = t >> 16;
    int c = (t >> 10) & 63;
    int p = t & 1023;
    int b = b0 + cb;
    int y = p >> 5, xx = p & 31;
    float acc = 0.f;
#pragma unroll
    for (int ky = 0; ky < 3; ++ky)
#pragma unroll
        for (int kx = 0; kx < 3; ++kx) {
            int py = y + 1 - ky, px = xx + 1 - kx;
            if (py >= 0 && py < HH && px >= 0 && px < WW)
                acc += outacc[((size_t)cb * 576 + c * 9 + ky * 3 + kx) * HW + py * WW + px];
        }
    size_t o = ((size_t)b * CC + c) * HW + p;
    out[o] = x[o] + 0.25f * acc;
}

extern "C" void kernel_launch(void* const* d_in, const int* in_sizes, int n_in,
                              void* d_out, int out_size, void* d_ws, size_t ws_size,
                              hipStream_t stream) {
    const float* x       = (const float*)d_in[0];
    const float* w_base  = (const float*)d_in[1];
    const float* b_base  = (const float*)d_in[2];
    const float* a_base  = (const float*)d_in[3];
    const float* w_match = (const float*)d_in[4];
    const float* b_match = (const float*)d_in[5];
    const float* a_match = (const float*)d_in[6];
    const float* w_asm   = (const float*)d_in[7];
    const float* b_asm   = (const float*)d_in[8];
    const float* a_asm   = (const float*)d_in[9];
    float* out = (float*)d_out;

    char* ws = (char*)d_ws;
    size_t off = 0;
    auto alloc_f = [&](size_t count) {
        float* p = (float*)(ws + off);
        off += count * sizeof(float);
        off = (off + 255) & ~(size_t)255;
        return p;
    };
    float* mb     = alloc_f((size_t)BB * C2 * HW);        //   4.2 MB
    float* refm   = alloc_f((size_t)BB * C2 * NTOT);      //  13.4 MB
    float* base_a = alloc_f((size_t)BB * CC * NTOT);      //  26.8 MB
    float* sinv   = alloc_f((size_t)BB * NTOT);           //   0.4 MB
    int*   nbr    = (int*)(ws + off);
    off += (size_t)9 * NTOT * sizeof(int);
    off = (off + 255) & ~(size_t)255;
    float* yi     = alloc_f((size_t)CBATCH * HW * NPAD);  //  53.7 MB
    float* outacc = alloc_f((size_t)CBATCH * 576 * HW);   //   9.4 MB
    if (off > ws_size) return;  // workspace too small: fail loudly (output untouched)

    k_match_base<<<BB * HW / 256, 256, 0, stream>>>(x, w_base, b_base, a_base, mb);
    k_scale_feats<<<(BB * NTOT + 255) / 256, 256, 0, stream>>>(
        x, w_match, b_match, a_match, w_asm, b_asm, a_asm, refm, base_a);
    k_nbr<<<(NTOT + 255) / 256, 256, 0, stream>>>(nbr);
    k_norms<<<(BB * NTOT + 255) / 256, 256, 0, stream>>>(refm, nbr, sinv);

    for (int b0 = 0; b0 < BB; b0 += CBATCH) {
        k_corr<<<dim3(16, (NTOT + 63) / 64, CBATCH), 256, 0, stream>>>(mb, refm, nbr, sinv, yi, b0);
        k_softmax<<<CBATCH * HW, 256, 0, stream>>>(yi);
        k_fold<<<dim3(16, 9, CBATCH), 256, 0, stream>>>(base_a, nbr, yi, outacc, b0);
        k_epilogue<<<CBATCH * CC * HW / 256, 256, 0, stream>>>(x, outacc, out, b0);
    }
}

// Round 2
// 2478.755 us; speedup vs baseline: 2.9432x; 2.9432x over previous
//
#include <hip/hip_runtime.h>
#include <hip/hip_bf16.h>
#include <math.h>

#define BB 32
#define CC 64
#define C2 32
#define HH 32
#define WW 32
#define HW 1024
#define NTOT 3278
#define NPAD 3280
#define NPAD2 3328   // K padding for MFMA fold (multiple of 128)
#define CBATCH 4
#define KT 32

typedef __bf16 bf16x8 __attribute__((ext_vector_type(8)));
typedef float  f32x4  __attribute__((ext_vector_type(4)));

__device__ __constant__ int SC_SIZE[5] = {32, 28, 25, 22, 19};
__device__ __constant__ int SC_OFF[6]  = {0, 1024, 1808, 2433, 2917, 3278};

// ---------------- stage A: match_base = PReLU(conv1x1(x, w_base)) ----------------
__global__ void k_match_base(const float* __restrict__ x, const float* __restrict__ w,
                             const float* __restrict__ bias, const float* __restrict__ a,
                             float* __restrict__ mb) {
    int t = blockIdx.x * blockDim.x + threadIdx.x;
    int b = t >> 10, p = t & 1023;
    float alpha = a[0];
    float xv[CC];
    const float* xb = x + (size_t)b * CC * HW + p;
#pragma unroll
    for (int c = 0; c < CC; ++c) xv[c] = xb[c * HW];
    for (int o = 0; o < C2; ++o) {
        float acc = bias[o];
#pragma unroll
        for (int c = 0; c < CC; ++c) acc += w[o * CC + c] * xv[c];
        mb[((size_t)b * C2 + o) * HW + p] = acc >= 0.f ? acc : alpha * acc;
    }
}

// ---------------- stage B: per-scale refm (fp32) / base (bf16) features ----------------
__global__ void k_scale_feats(const float* __restrict__ x,
                              const float* __restrict__ wm, const float* __restrict__ bm, const float* __restrict__ am,
                              const float* __restrict__ wa, const float* __restrict__ ba, const float* __restrict__ aa,
                              float* __restrict__ refm, __bf16* __restrict__ base) {
    int t = blockIdx.x * blockDim.x + threadIdx.x;
    if (t >= BB * NTOT) return;
    int b = t / NTOT, n = t % NTOT;
    int s = 0;
    while (s < 4 && n >= SC_OFF[s + 1]) ++s;
    int q = n - SC_OFF[s];
    int hs = SC_SIZE[s];
    int ny = q / hs, nx = q % hs;
    int iy = (ny * HH) / hs, ix = (nx * WW) / hs;
    const float* xb = x + (size_t)b * CC * HW + iy * WW + ix;
    float xv[CC];
#pragma unroll
    for (int c = 0; c < CC; ++c) xv[c] = xb[c * HW];
    float alm = am[0], ala = aa[0];
    for (int o = 0; o < CC; ++o) {
        float acc = ba[o];
#pragma unroll
        for (int c = 0; c < CC; ++c) acc += wa[o * CC + c] * xv[c];
        base[((size_t)b * CC + o) * NTOT + n] = (__bf16)(acc >= 0.f ? acc : ala * acc);
    }
    for (int o = 0; o < C2; ++o) {
        float acc = bm[o];
#pragma unroll
        for (int c = 0; c < CC; ++c) acc += wm[o * CC + c] * xv[c];
        refm[((size_t)b * C2 + o) * NTOT + n] = acc >= 0.f ? acc : alm * acc;
    }
}

// ---------------- neighbor table ----------------
__global__ void k_nbr(int* __restrict__ nbr) {
    int n = blockIdx.x * blockDim.x + threadIdx.x;
    if (n >= NTOT) return;
    int s = 0;
    while (s < 4 && n >= SC_OFF[s + 1]) ++s;
    int q = n - SC_OFF[s];
    int hs = SC_SIZE[s];
    int ny = q / hs, nx = q % hs;
    for (int dy = 0; dy < 3; ++dy)
        for (int dx = 0; dx < 3; ++dx) {
            int yy = ny + dy - 1, xx = nx + dx - 1;
            int idx = (yy >= 0 && yy < hs && xx >= 0 && xx < hs) ? (SC_OFF[s] + yy * hs + xx) : -1;
            nbr[(dy * 3 + dx) * NTOT + n] = idx;
        }
}

// ---------------- per-(b,n) filter norms; sinv = 10 / max(norm, 1e-4) ----------------
__global__ void k_norms(const float* __restrict__ refm, const int* __restrict__ nbr,
                        float* __restrict__ sinv) {
    int t = blockIdx.x * blockDim.x + threadIdx.x;
    if (t >= BB * NTOT) return;
    int b = t / NTOT, n = t % NTOT;
    float sum = 0.f;
    for (int kk = 0; kk < 9; ++kk) {
        int idx = nbr[kk * NTOT + n];
        if (idx < 0) continue;
        const float* r = refm + (size_t)b * C2 * NTOT + idx;
#pragma unroll
        for (int c = 0; c < C2; ++c) {
            float v = r[(size_t)c * NTOT];
            sum += v * v;
        }
    }
    sinv[t] = 10.0f / fmaxf(sqrtf(sum), 1e-4f);
}

// ---------------- correlation GEMM (fp32 VALU): yi[cb][p][n] ----------------
__global__ void k_corr(const float* __restrict__ mb, const float* __restrict__ refm,
                       const int* __restrict__ nbr, const float* __restrict__ sinv,
                       float* __restrict__ yi, int b0) {
    int cb = blockIdx.z, b = b0 + cb;
    int p0 = blockIdx.x * 64, n0 = blockIdx.y * 64;
    int tid = threadIdx.x;
    int ty = tid >> 4, tx = tid & 15;
    __shared__ float As[KT][64];
    __shared__ float Bs[KT][64];
    float acc[4][4] = {};
    const float* mbb = mb + (size_t)b * C2 * HW;
    const float* rmb = refm + (size_t)b * C2 * NTOT;
    for (int k0 = 0; k0 < 288; k0 += KT) {
        for (int e = tid; e < KT * 64; e += 256) {
            int kt = e >> 6, i = e & 63;
            int k = k0 + kt;
            int c2 = k / 9, kk = k % 9;
            int p = p0 + i;
            int py = (p >> 5) + kk / 3 - 1;
            int px = (p & 31) + kk % 3 - 1;
            float v = 0.f;
            if (py >= 0 && py < HH && px >= 0 && px < WW)
                v = mbb[(size_t)c2 * HW + py * WW + px];
            As[kt][i] = v;
        }
        for (int e = tid; e < KT * 64; e += 256) {
            int kt = e >> 6, j = e & 63;
            int k = k0 + kt;
            int c2 = k / 9, kk = k % 9;
            int n = n0 + j;
            float v = 0.f;
            if (n < NTOT) {
                int idx = nbr[kk * NTOT + n];
                if (idx >= 0) v = rmb[(size_t)c2 * NTOT + idx];
            }
            Bs[kt][j] = v;
        }
        __syncthreads();
#pragma unroll 8
        for (int kt = 0; kt < KT; ++kt) {
            float av[4], bv[4];
#pragma unroll
            for (int ii = 0; ii < 4; ++ii) av[ii] = As[kt][ty * 4 + ii];
#pragma unroll
            for (int jj = 0; jj < 4; ++jj) bv[jj] = Bs[kt][tx * 4 + jj];
#pragma unroll
            for (int ii = 0; ii < 4; ++ii)
#pragma unroll
                for (int jj = 0; jj < 4; ++jj) acc[ii][jj] += av[ii] * bv[jj];
        }
        __syncthreads();
    }
#pragma unroll
    for (int ii = 0; ii < 4; ++ii) {
        int p = p0 + ty * 4 + ii;
#pragma unroll
        for (int jj = 0; jj < 4; ++jj) {
            int n = n0 + tx * 4 + jj;
            if (n < NTOT)
                yi[((size_t)cb * HW + p) * NPAD + n] = acc[ii][jj] * sinv[(size_t)b * NTOT + n];
        }
    }
}

// ---------------- softmax over n; writes bf16 prob with zero K-padding ----------------
__global__ void k_softmax(const float* __restrict__ yi, __bf16* __restrict__ prob) {
    const float* r = yi + (size_t)blockIdx.x * NPAD;
    __bf16* pr = prob + (size_t)blockIdx.x * NPAD2;
    __shared__ float red[256];
    int tid = threadIdx.x;
    float m = -1e30f;
    for (int n = tid; n < NTOT; n += 256) m = fmaxf(m, r[n]);
    red[tid] = m;
    __syncthreads();
    for (int s = 128; s > 0; s >>= 1) {
        if (tid < s) red[tid] = fmaxf(red[tid], red[tid + s]);
        __syncthreads();
    }
    m = red[0];
    __syncthreads();
    float sum = 0.f;
    for (int n = tid; n < NTOT; n += 256) sum += __expf(r[n] - m);
    red[tid] = sum;
    __syncthreads();
    for (int s = 128; s > 0; s >>= 1) {
        if (tid < s) red[tid] += red[tid + s];
        __syncthreads();
    }
    float inv = 1.0f / red[0];
    for (int n = tid; n < NPAD2; n += 256)
        pr[n] = (n < NTOT) ? (__bf16)(__expf(r[n] - m) * inv) : (__bf16)0.f;
}

// ---------------- V gather: Vb[cb][m=576][NPAD2] bf16 ----------------
__global__ void k_vgather(const __bf16* __restrict__ base, const int* __restrict__ nbr,
                          __bf16* __restrict__ Vb, int b0) {
    int n = blockIdx.x * 256 + threadIdx.x;   // 0..NPAD2 (13*256=3328)
    int m = blockIdx.y;                        // 0..575
    int cb = blockIdx.z;
    int c = m / 9, kk = m % 9;
    __bf16 v = (__bf16)0.f;
    if (n < NTOT) {
        int idx = nbr[kk * NTOT + n];
        if (idx >= 0) v = base[((size_t)(b0 + cb) * CC + c) * NTOT + idx];
    }
    Vb[((size_t)cb * 576 + m) * NPAD2 + n] = v;
}

// ---------------- fold GEMM (MFMA bf16): outacc[cb][m][p] = sum_n V[m,n]*prob[p,n] ----------------
// block: 256 thr = 4 waves; tile M=64(m) x N=128(p); K-loop over NPAD2 in steps of 32.
__global__ void k_fold_mfma(const __bf16* __restrict__ Vb, const __bf16* __restrict__ prob,
                            float* __restrict__ outacc) {
    int ptile = blockIdx.x;   // 0..7   (p0 = ptile*128)
    int mtile = blockIdx.y;   // 0..8   (m0 = mtile*64)
    int cb    = blockIdx.z;
    int tid  = threadIdx.x;
    int lane = tid & 63, wave = tid >> 6;
    int row16 = lane & 15, quad = lane >> 4;

    __shared__ __bf16 Als[64 * 40];    // row stride 40 bf16 (80 B, 16B-aligned)
    __shared__ __bf16 Bls[128 * 40];

    const __bf16* Vp = Vb   + (size_t)cb * 576 * NPAD2 + (size_t)mtile * 64 * NPAD2;
    const __bf16* Pp = prob + (size_t)cb * HW  * NPAD2 + (size_t)ptile * 128 * NPAD2;

    f32x4 acc[4][2];
#pragma unroll
    for (int i = 0; i < 4; ++i)
#pragma unroll
        for (int j = 0; j < 2; ++j) acc[i][j] = (f32x4){0.f, 0.f, 0.f, 0.f};

    int lm = tid >> 2, lkq = (tid & 3) * 8;   // staging coords: V rows
    for (int k0 = 0; k0 < NPAD2; k0 += 32) {
        // stage V tile: 64 rows x 32 k  (one 16B load/thread)
        *(bf16x8*)&Als[lm * 40 + lkq] = *(const bf16x8*)(Vp + (size_t)lm * NPAD2 + k0 + lkq);
        // stage prob tile: 128 rows x 32 k (two 16B loads/thread)
#pragma unroll
        for (int i = 0; i < 2; ++i) {
            int r = tid + i * 256;
            int p = r >> 2, kq = (r & 3) * 8;
            *(bf16x8*)&Bls[p * 40 + kq] = *(const bf16x8*)(Pp + (size_t)p * NPAD2 + k0 + kq);
        }
        __syncthreads();
        bf16x8 af[4], bf[2];
#pragma unroll
        for (int mb = 0; mb < 4; ++mb)
            af[mb] = *(const bf16x8*)&Als[(mb * 16 + row16) * 40 + quad * 8];
#pragma unroll
        for (int pb = 0; pb < 2; ++pb)
            bf[pb] = *(const bf16x8*)&Bls[(wave * 32 + pb * 16 + row16) * 40 + quad * 8];
#pragma unroll
        for (int mb = 0; mb < 4; ++mb)
#pragma unroll
            for (int pb = 0; pb < 2; ++pb)
                acc[mb][pb] = __builtin_amdgcn_mfma_f32_16x16x32_bf16(af[mb], bf[pb], acc[mb][pb], 0, 0, 0);
        __syncthreads();
    }
    // D layout: col(p) = lane&15, row(m) = quad*4 + reg
#pragma unroll
    for (int mb = 0; mb < 4; ++mb)
#pragma unroll
        for (int pb = 0; pb < 2; ++pb) {
#pragma unroll
            for (int r = 0; r < 4; ++r) {
                int mg = mtile * 64 + mb * 16 + quad * 4 + r;
                int pg = ptile * 128 + wave * 32 + pb * 16 + row16;
                outacc[((size_t)cb * 576 + mg) * HW + pg] = acc[mb][pb][r];
            }
        }
}

// ---------------- epilogue ----------------
__global__ void k_epilogue(const float* __restrict__ x, const float* __restrict__ outacc,
                           float* __restrict__ out, int b0) {
    int t = blockIdx.x * blockDim.x + threadIdx.x;
    int cb = t >> 16;
    int c = (t >> 10) & 63;
    int p = t & 1023;
    int b = b0 + cb;
    int y = p >> 5, xx = p & 31;
    float acc = 0.f;
#pragma unroll
    for (int ky = 0; ky < 3; ++ky)
#pragma unroll
        for (int kx = 0; kx < 3; ++kx) {
            int py = y + 1 - ky, px = xx + 1 - kx;
            if (py >= 0 && py < HH && px >= 0 && px < WW)
                acc += outacc[((size_t)cb * 576 + c * 9 + ky * 3 + kx) * HW + py * WW + px];
        }
    size_t o = ((size_t)b * CC + c) * HW + p;
    out[o] = x[o] + 0.25f * acc;
}

extern "C" void kernel_launch(void* const* d_in, const int* in_sizes, int n_in,
                              void* d_out, int out_size, void* d_ws, size_t ws_size,
                              hipStream_t stream) {
    const float* x       = (const float*)d_in[0];
    const float* w_base  = (const float*)d_in[1];
    const float* b_base  = (const float*)d_in[2];
    const float* a_base  = (const float*)d_in[3];
    const float* w_match = (const float*)d_in[4];
    const float* b_match = (const float*)d_in[5];
    const float* a_match = (const float*)d_in[6];
    const float* w_asm   = (const float*)d_in[7];
    const float* b_asm   = (const float*)d_in[8];
    const float* a_asm   = (const float*)d_in[9];
    float* out = (float*)d_out;

    char* ws = (char*)d_ws;
    size_t off = 0;
    auto alloc_b = [&](size_t bytes) {
        void* p = (void*)(ws + off);
        off += bytes;
        off = (off + 255) & ~(size_t)255;
        return p;
    };
    float*  mb      = (float*)alloc_b((size_t)BB * C2 * HW * 4);        //   4.2 MB
    float*  refm    = (float*)alloc_b((size_t)BB * C2 * NTOT * 4);      //  13.4 MB
    __bf16* base_bf = (__bf16*)alloc_b((size_t)BB * CC * NTOT * 2);     //  13.4 MB
    float*  sinv    = (float*)alloc_b((size_t)BB * NTOT * 4);           //   0.4 MB
    int*    nbr     = (int*)alloc_b((size_t)9 * NTOT * 4);              //   0.1 MB
    float*  yi      = (float*)alloc_b((size_t)CBATCH * HW * NPAD * 4);  //  53.7 MB
    __bf16* prob    = (__bf16*)alloc_b((size_t)CBATCH * HW * NPAD2 * 2);//  27.3 MB
    __bf16* Vb      = (__bf16*)alloc_b((size_t)CBATCH * 576 * NPAD2 * 2);// 15.3 MB
    float*  outacc  = (float*)alloc_b((size_t)CBATCH * 576 * HW * 4);   //   9.4 MB
    if (off > ws_size) return;  // workspace too small: fail loudly

    k_match_base<<<BB * HW / 256, 256, 0, stream>>>(x, w_base, b_base, a_base, mb);
    k_scale_feats<<<(BB * NTOT + 255) / 256, 256, 0, stream>>>(
        x, w_match, b_match, a_match, w_asm, b_asm, a_asm, refm, base_bf);
    k_nbr<<<(NTOT + 255) / 256, 256, 0, stream>>>(nbr);
    k_norms<<<(BB * NTOT + 255) / 256, 256, 0, stream>>>(refm, nbr, sinv);

    for (int b0 = 0; b0 < BB; b0 += CBATCH) {
        k_corr<<<dim3(16, (NTOT + 63) / 64, CBATCH), 256, 0, stream>>>(mb, refm, nbr, sinv, yi, b0);
        k_softmax<<<CBATCH * HW, 256, 0, stream>>>(yi, prob);
        k_vgather<<<dim3(NPAD2 / 256, 576, CBATCH), 256, 0, stream>>>(base_bf, nbr, Vb, b0);
        k_fold_mfma<<<dim3(8, 9, CBATCH), 256, 0, stream>>>(Vb, prob, outacc);
        k_epilogue<<<CBATCH * CC * HW / 256, 256, 0, stream>>>(x, outacc, out, b0);
    }
}

// Round 3
// 1618.851 us; speedup vs baseline: 4.5065x; 1.5312x over previous
//
#include <hip/hip_runtime.h>
#include <hip/hip_bf16.h>
#include <math.h>

#define BB 32
#define CC 64
#define C2 32
#define HH 32
#define WW 32
#define HW 1024
#define NTOT 3278
#define NPAD2 3328   // padded N (multiple of 128) for MFMA corr + fold
#define KC 288       // correlation K = C2*9
#define CBATCH 4

typedef __bf16 bf16x8 __attribute__((ext_vector_type(8)));
typedef float  f32x4  __attribute__((ext_vector_type(4)));

__device__ __constant__ int SC_SIZE[5] = {32, 28, 25, 22, 19};
__device__ __constant__ int SC_OFF[6]  = {0, 1024, 1808, 2433, 2917, 3278};

// ---------------- stage A: match_base = PReLU(conv1x1(x, w_base)) ----------------
__global__ void k_match_base(const float* __restrict__ x, const float* __restrict__ w,
                             const float* __restrict__ bias, const float* __restrict__ a,
                             float* __restrict__ mb) {
    int t = blockIdx.x * blockDim.x + threadIdx.x;
    int b = t >> 10, p = t & 1023;
    float alpha = a[0];
    float xv[CC];
    const float* xb = x + (size_t)b * CC * HW + p;
#pragma unroll
    for (int c = 0; c < CC; ++c) xv[c] = xb[c * HW];
    for (int o = 0; o < C2; ++o) {
        float acc = bias[o];
#pragma unroll
        for (int c = 0; c < CC; ++c) acc += w[o * CC + c] * xv[c];
        mb[((size_t)b * C2 + o) * HW + p] = acc >= 0.f ? acc : alpha * acc;
    }
}

// ---------------- stage B: per-scale refm (fp32) / base (bf16) features ----------------
__global__ void k_scale_feats(const float* __restrict__ x,
                              const float* __restrict__ wm, const float* __restrict__ bm, const float* __restrict__ am,
                              const float* __restrict__ wa, const float* __restrict__ ba, const float* __restrict__ aa,
                              float* __restrict__ refm, __bf16* __restrict__ base) {
    int t = blockIdx.x * blockDim.x + threadIdx.x;
    if (t >= BB * NTOT) return;
    int b = t / NTOT, n = t % NTOT;
    int s = 0;
    while (s < 4 && n >= SC_OFF[s + 1]) ++s;
    int q = n - SC_OFF[s];
    int hs = SC_SIZE[s];
    int ny = q / hs, nx = q % hs;
    int iy = (ny * HH) / hs, ix = (nx * WW) / hs;
    const float* xb = x + (size_t)b * CC * HW + iy * WW + ix;
    float xv[CC];
#pragma unroll
    for (int c = 0; c < CC; ++c) xv[c] = xb[c * HW];
    float alm = am[0], ala = aa[0];
    for (int o = 0; o < CC; ++o) {
        float acc = ba[o];
#pragma unroll
        for (int c = 0; c < CC; ++c) acc += wa[o * CC + c] * xv[c];
        base[((size_t)b * CC + o) * NTOT + n] = (__bf16)(acc >= 0.f ? acc : ala * acc);
    }
    for (int o = 0; o < C2; ++o) {
        float acc = bm[o];
#pragma unroll
        for (int c = 0; c < CC; ++c) acc += wm[o * CC + c] * xv[c];
        refm[((size_t)b * C2 + o) * NTOT + n] = acc >= 0.f ? acc : alm * acc;
    }
}

// ---------------- neighbor table ----------------
__global__ void k_nbr(int* __restrict__ nbr) {
    int n = blockIdx.x * blockDim.x + threadIdx.x;
    if (n >= NTOT) return;
    int s = 0;
    while (s < 4 && n >= SC_OFF[s + 1]) ++s;
    int q = n - SC_OFF[s];
    int hs = SC_SIZE[s];
    int ny = q / hs, nx = q % hs;
    for (int dy = 0; dy < 3; ++dy)
        for (int dx = 0; dx < 3; ++dx) {
            int yy = ny + dy - 1, xx = nx + dx - 1;
            int idx = (yy >= 0 && yy < hs && xx >= 0 && xx < hs) ? (SC_OFF[s] + yy * hs + xx) : -1;
            nbr[(dy * 3 + dx) * NTOT + n] = idx;
        }
}

// ---------------- per-(b,n) filter norms; sinv = 10 / max(norm, 1e-4) ----------------
__global__ void k_norms(const float* __restrict__ refm, const int* __restrict__ nbr,
                        float* __restrict__ sinv) {
    int t = blockIdx.x * blockDim.x + threadIdx.x;
    if (t >= BB * NTOT) return;
    int b = t / NTOT, n = t % NTOT;
    float sum = 0.f;
    for (int kk = 0; kk < 9; ++kk) {
        int idx = nbr[kk * NTOT + n];
        if (idx < 0) continue;
        const float* r = refm + (size_t)b * C2 * NTOT + idx;
#pragma unroll
        for (int c = 0; c < C2; ++c) {
            float v = r[(size_t)c * NTOT];
            sum += v * v;
        }
    }
    sinv[t] = 10.0f / fmaxf(sqrtf(sum), 1e-4f);
}

// ---------------- xpat gather: match_base patches -> [cb][p][KC] bf16 hi/lo ----------------
__global__ void k_xpat(const float* __restrict__ mb, __bf16* __restrict__ xh,
                       __bf16* __restrict__ xl, int b0) {
    int t = blockIdx.x * 256 + threadIdx.x;   // over HW*KC = 294912
    int cb = blockIdx.y;
    int p = t / KC, k = t % KC;
    int c2 = k / 9, kk = k % 9;
    int py = (p >> 5) + kk / 3 - 1;
    int px = (p & 31) + kk % 3 - 1;
    float v = 0.f;
    if (py >= 0 && py < HH && px >= 0 && px < WW)
        v = mb[((size_t)(b0 + cb) * C2 + c2) * HW + py * WW + px];
    __bf16 hi = (__bf16)v;
    size_t o = ((size_t)cb * HW + p) * KC + k;
    xh[o] = hi;
    xl[o] = (__bf16)(v - (float)hi);
}

// ---------------- wib gather: wi rows -> [cb][n][KC] bf16 hi/lo (zero-padded n) ----------------
__global__ void k_wib(const float* __restrict__ refm, const int* __restrict__ nbr,
                      __bf16* __restrict__ wh, __bf16* __restrict__ wl, int b0) {
    int t = blockIdx.x * 256 + threadIdx.x;   // over NPAD2*KC = 958464
    int cb = blockIdx.y;
    int n = t / KC, k = t % KC;
    int c2 = k / 9, kk = k % 9;
    float v = 0.f;
    if (n < NTOT) {
        int idx = nbr[kk * NTOT + n];
        if (idx >= 0) v = refm[((size_t)(b0 + cb) * C2 + c2) * NTOT + idx];
    }
    __bf16 hi = (__bf16)v;
    size_t o = ((size_t)cb * NPAD2 + n) * KC + k;
    wh[o] = hi;
    wl[o] = (__bf16)(v - (float)hi);
}

// ---------------- correlation GEMM (MFMA, split-bf16): yi[cb][p][n] = sinv*sum_k xp*wi ----------------
// block 256 thr = 4 waves; tile M=64(p) x N=128(n); acc = Ah*Bh + Ah*Bl + Al*Bh.
__global__ void k_corr_mfma(const __bf16* __restrict__ xh, const __bf16* __restrict__ xl,
                            const __bf16* __restrict__ wh, const __bf16* __restrict__ wl,
                            const float* __restrict__ sinv, float* __restrict__ yi, int b0) {
    int ptile = blockIdx.x;   // 16 tiles of 64 p
    int ntile = blockIdx.y;   // 26 tiles of 128 n
    int cb    = blockIdx.z;
    int tid  = threadIdx.x;
    int lane = tid & 63, wave = tid >> 6;
    int row16 = lane & 15, quad = lane >> 4;

    __shared__ __bf16 Ah[64 * 40], Al[64 * 40];
    __shared__ __bf16 Bh[128 * 40], Bl[128 * 40];

    const __bf16* Aph = xh + ((size_t)cb * HW + ptile * 64) * KC;
    const __bf16* Apl = xl + ((size_t)cb * HW + ptile * 64) * KC;
    const __bf16* Bph = wh + ((size_t)cb * NPAD2 + ntile * 128) * KC;
    const __bf16* Bpl = wl + ((size_t)cb * NPAD2 + ntile * 128) * KC;

    f32x4 acc[4][2];
#pragma unroll
    for (int i = 0; i < 4; ++i)
#pragma unroll
        for (int j = 0; j < 2; ++j) acc[i][j] = (f32x4){0.f, 0.f, 0.f, 0.f};

    int lr = tid >> 2, lk = (tid & 3) * 8;
    for (int k0 = 0; k0 < KC; k0 += 32) {
        *(bf16x8*)&Ah[lr * 40 + lk] = *(const bf16x8*)(Aph + (size_t)lr * KC + k0 + lk);
        *(bf16x8*)&Al[lr * 40 + lk] = *(const bf16x8*)(Apl + (size_t)lr * KC + k0 + lk);
#pragma unroll
        for (int i = 0; i < 2; ++i) {
            int r = tid + i * 256;
            int rr = r >> 2, rk = (r & 3) * 8;
            *(bf16x8*)&Bh[rr * 40 + rk] = *(const bf16x8*)(Bph + (size_t)rr * KC + k0 + rk);
            *(bf16x8*)&Bl[rr * 40 + rk] = *(const bf16x8*)(Bpl + (size_t)rr * KC + k0 + rk);
        }
        __syncthreads();
        bf16x8 ah[4], al[4], bh[2], bl[2];
#pragma unroll
        for (int m = 0; m < 4; ++m) {
            ah[m] = *(const bf16x8*)&Ah[(m * 16 + row16) * 40 + quad * 8];
            al[m] = *(const bf16x8*)&Al[(m * 16 + row16) * 40 + quad * 8];
        }
#pragma unroll
        for (int nb = 0; nb < 2; ++nb) {
            bh[nb] = *(const bf16x8*)&Bh[(wave * 32 + nb * 16 + row16) * 40 + quad * 8];
            bl[nb] = *(const bf16x8*)&Bl[(wave * 32 + nb * 16 + row16) * 40 + quad * 8];
        }
#pragma unroll
        for (int m = 0; m < 4; ++m)
#pragma unroll
            for (int nb = 0; nb < 2; ++nb) {
                acc[m][nb] = __builtin_amdgcn_mfma_f32_16x16x32_bf16(ah[m], bh[nb], acc[m][nb], 0, 0, 0);
                acc[m][nb] = __builtin_amdgcn_mfma_f32_16x16x32_bf16(ah[m], bl[nb], acc[m][nb], 0, 0, 0);
                acc[m][nb] = __builtin_amdgcn_mfma_f32_16x16x32_bf16(al[m], bh[nb], acc[m][nb], 0, 0, 0);
            }
        __syncthreads();
    }
    // D layout: col(n) = lane&15, row(p) = quad*4 + reg
#pragma unroll
    for (int nb = 0; nb < 2; ++nb) {
        int n = ntile * 128 + wave * 32 + nb * 16 + row16;
        float sv = (n < NTOT) ? sinv[(size_t)(b0 + cb) * NTOT + n] : 0.f;
#pragma unroll
        for (int m = 0; m < 4; ++m)
#pragma unroll
            for (int r = 0; r < 4; ++r) {
                int p = ptile * 64 + m * 16 + quad * 4 + r;
                yi[((size_t)cb * HW + p) * NPAD2 + n] = acc[m][nb][r] * sv;
            }
    }
}

// ---------------- softmax over n (online max+sum, 2 read passes); bf16 prob out ----------------
__global__ void k_softmax(const float* __restrict__ yi, __bf16* __restrict__ prob) {
    const float* r = yi + (size_t)blockIdx.x * NPAD2;
    __bf16* pr = prob + (size_t)blockIdx.x * NPAD2;
    __shared__ float red_m[256], red_s[256];
    int tid = threadIdx.x;
    float m = -1e30f, s = 0.f;
    for (int n = tid; n < NTOT; n += 256) {
        float v = r[n];
        if (v > m) { s = s * __expf(m - v) + 1.f; m = v; }
        else s += __expf(v - m);
    }
    red_m[tid] = m; red_s[tid] = s;
    __syncthreads();
    for (int st = 128; st > 0; st >>= 1) {
        if (tid < st) {
            float m2 = red_m[tid + st], s2 = red_s[tid + st];
            float M = fmaxf(red_m[tid], m2);
            red_s[tid] = red_s[tid] * __expf(red_m[tid] - M) + s2 * __expf(m2 - M);
            red_m[tid] = M;
        }
        __syncthreads();
    }
    m = red_m[0];
    float inv = 1.0f / red_s[0];
    for (int n = tid; n < NPAD2; n += 256)
        pr[n] = (n < NTOT) ? (__bf16)(__expf(r[n] - m) * inv) : (__bf16)0.f;
}

// ---------------- V gather: Vb[cb][m=576][NPAD2] bf16 ----------------
__global__ void k_vgather(const __bf16* __restrict__ base, const int* __restrict__ nbr,
                          __bf16* __restrict__ Vb, int b0) {
    int n = blockIdx.x * 256 + threadIdx.x;
    int m = blockIdx.y;
    int cb = blockIdx.z;
    int c = m / 9, kk = m % 9;
    __bf16 v = (__bf16)0.f;
    if (n < NTOT) {
        int idx = nbr[kk * NTOT + n];
        if (idx >= 0) v = base[((size_t)(b0 + cb) * CC + c) * NTOT + idx];
    }
    Vb[((size_t)cb * 576 + m) * NPAD2 + n] = v;
}

// ---------------- fold GEMM (MFMA bf16): outacc[cb][m][p] = sum_n V[m,n]*prob[p,n] ----------------
__global__ void k_fold_mfma(const __bf16* __restrict__ Vb, const __bf16* __restrict__ prob,
                            float* __restrict__ outacc) {
    int ptile = blockIdx.x;   // 8 tiles of 128 p
    int mtile = blockIdx.y;   // 9 tiles of 64 m
    int cb    = blockIdx.z;
    int tid  = threadIdx.x;
    int lane = tid & 63, wave = tid >> 6;
    int row16 = lane & 15, quad = lane >> 4;

    __shared__ __bf16 Als[64 * 40];
    __shared__ __bf16 Bls[128 * 40];

    const __bf16* Vp = Vb   + (size_t)cb * 576 * NPAD2 + (size_t)mtile * 64 * NPAD2;
    const __bf16* Pp = prob + (size_t)cb * HW  * NPAD2 + (size_t)ptile * 128 * NPAD2;

    f32x4 acc[4][2];
#pragma unroll
    for (int i = 0; i < 4; ++i)
#pragma unroll
        for (int j = 0; j < 2; ++j) acc[i][j] = (f32x4){0.f, 0.f, 0.f, 0.f};

    int lm = tid >> 2, lkq = (tid & 3) * 8;
    for (int k0 = 0; k0 < NPAD2; k0 += 32) {
        *(bf16x8*)&Als[lm * 40 + lkq] = *(const bf16x8*)(Vp + (size_t)lm * NPAD2 + k0 + lkq);
#pragma unroll
        for (int i = 0; i < 2; ++i) {
            int r = tid + i * 256;
            int p = r >> 2, kq = (r & 3) * 8;
            *(bf16x8*)&Bls[p * 40 + kq] = *(const bf16x8*)(Pp + (size_t)p * NPAD2 + k0 + kq);
        }
        __syncthreads();
        bf16x8 af[4], bf[2];
#pragma unroll
        for (int mb = 0; mb < 4; ++mb)
            af[mb] = *(const bf16x8*)&Als[(mb * 16 + row16) * 40 + quad * 8];
#pragma unroll
        for (int pb = 0; pb < 2; ++pb)
            bf[pb] = *(const bf16x8*)&Bls[(wave * 32 + pb * 16 + row16) * 40 + quad * 8];
#pragma unroll
        for (int mb = 0; mb < 4; ++mb)
#pragma unroll
            for (int pb = 0; pb < 2; ++pb)
                acc[mb][pb] = __builtin_amdgcn_mfma_f32_16x16x32_bf16(af[mb], bf[pb], acc[mb][pb], 0, 0, 0);
        __syncthreads();
    }
#pragma unroll
    for (int mb = 0; mb < 4; ++mb)
#pragma unroll
        for (int pb = 0; pb < 2; ++pb) {
#pragma unroll
            for (int r = 0; r < 4; ++r) {
                int mg = mtile * 64 + mb * 16 + quad * 4 + r;
                int pg = ptile * 128 + wave * 32 + pb * 16 + row16;
                outacc[((size_t)cb * 576 + mg) * HW + pg] = acc[mb][pb][r];
            }
        }
}

// ---------------- epilogue ----------------
__global__ void k_epilogue(const float* __restrict__ x, const float* __restrict__ outacc,
                           float* __restrict__ out, int b0) {
    int t = blockIdx.x * blockDim.x + threadIdx.x;
    int cb = t >> 16;
    int c = (t >> 10) & 63;
    int p = t & 1023;
    int b = b0 + cb;
    int y = p >> 5, xx = p & 31;
    float acc = 0.f;
#pragma unroll
    for (int ky = 0; ky < 3; ++ky)
#pragma unroll
        for (int kx = 0; kx < 3; ++kx) {
            int py = y + 1 - ky, px = xx + 1 - kx;
            if (py >= 0 && py < HH && px >= 0 && px < WW)
                acc += outacc[((size_t)cb * 576 + c * 9 + ky * 3 + kx) * HW + py * WW + px];
        }
    size_t o = ((size_t)b * CC + c) * HW + p;
    out[o] = x[o] + 0.25f * acc;
}

extern "C" void kernel_launch(void* const* d_in, const int* in_sizes, int n_in,
                              void* d_out, int out_size, void* d_ws, size_t ws_size,
                              hipStream_t stream) {
    const float* x       = (const float*)d_in[0];
    const float* w_base  = (const float*)d_in[1];
    const float* b_base  = (const float*)d_in[2];
    const float* a_base  = (const float*)d_in[3];
    const float* w_match = (const float*)d_in[4];
    const float* b_match = (const float*)d_in[5];
    const float* a_match = (const float*)d_in[6];
    const float* w_asm   = (const float*)d_in[7];
    const float* b_asm   = (const float*)d_in[8];
    const float* a_asm   = (const float*)d_in[9];
    float* out = (float*)d_out;

    char* ws = (char*)d_ws;
    size_t off = 0;
    auto alloc_b = [&](size_t bytes) {
        void* p = (void*)(ws + off);
        off += bytes;
        off = (off + 255) & ~(size_t)255;
        return p;
    };
    float*  mb      = (float*)alloc_b((size_t)BB * C2 * HW * 4);          //   4.2 MB
    float*  refm    = (float*)alloc_b((size_t)BB * C2 * NTOT * 4);        //  13.4 MB
    __bf16* base_bf = (__bf16*)alloc_b((size_t)BB * CC * NTOT * 2);       //  13.4 MB
    float*  sinv    = (float*)alloc_b((size_t)BB * NTOT * 4);             //   0.4 MB
    int*    nbr     = (int*)alloc_b((size_t)9 * NTOT * 4);                //   0.1 MB
    __bf16* xpat_h  = (__bf16*)alloc_b((size_t)CBATCH * HW * KC * 2);     //   2.4 MB
    __bf16* xpat_l  = (__bf16*)alloc_b((size_t)CBATCH * HW * KC * 2);     //   2.4 MB
    __bf16* wib_h   = (__bf16*)alloc_b((size_t)CBATCH * NPAD2 * KC * 2);  //   7.7 MB
    __bf16* wib_l   = (__bf16*)alloc_b((size_t)CBATCH * NPAD2 * KC * 2);  //   7.7 MB
    float*  yi      = (float*)alloc_b((size_t)CBATCH * HW * NPAD2 * 4);   //  54.5 MB
    __bf16* prob    = (__bf16*)alloc_b((size_t)CBATCH * HW * NPAD2 * 2);  //  27.3 MB
    __bf16* Vb      = (__bf16*)alloc_b((size_t)CBATCH * 576 * NPAD2 * 2); //  15.3 MB
    float*  outacc  = (float*)alloc_b((size_t)CBATCH * 576 * HW * 4);     //   9.4 MB
    if (off > ws_size) return;  // ~158 MB total

    k_match_base<<<BB * HW / 256, 256, 0, stream>>>(x, w_base, b_base, a_base, mb);
    k_scale_feats<<<(BB * NTOT + 255) / 256, 256, 0, stream>>>(
        x, w_match, b_match, a_match, w_asm, b_asm, a_asm, refm, base_bf);
    k_nbr<<<(NTOT + 255) / 256, 256, 0, stream>>>(nbr);
    k_norms<<<(BB * NTOT + 255) / 256, 256, 0, stream>>>(refm, nbr, sinv);

    for (int b0 = 0; b0 < BB; b0 += CBATCH) {
        k_xpat<<<dim3(HW * KC / 256, CBATCH), 256, 0, stream>>>(mb, xpat_h, xpat_l, b0);
        k_wib<<<dim3(NPAD2 * KC / 256, CBATCH), 256, 0, stream>>>(refm, nbr, wib_h, wib_l, b0);
        k_corr_mfma<<<dim3(16, NPAD2 / 128, CBATCH), 256, 0, stream>>>(
            xpat_h, xpat_l, wib_h, wib_l, sinv, yi, b0);
        k_softmax<<<CBATCH * HW, 256, 0, stream>>>(yi, prob);
        k_vgather<<<dim3(NPAD2 / 256, 576, CBATCH), 256, 0, stream>>>(base_bf, nbr, Vb, b0);
        k_fold_mfma<<<dim3(8, 9, CBATCH), 256, 0, stream>>>(Vb, prob, outacc);
        k_epilogue<<<CBATCH * CC * HW / 256, 256, 0, stream>>>(x, outacc, out, b0);
    }
}

// Round 4
// 1244.626 us; speedup vs baseline: 5.8615x; 1.3007x over previous
//
#include <hip/hip_runtime.h>
#include <hip/hip_bf16.h>
#include <math.h>

#define BB 32
#define CC 64
#define C2 32
#define HH 32
#define WW 32
#define HW 1024
#define NTOT 3278
#define NPAD2 3328   // padded N (multiple of 128) for MFMA corr + fold
#define NT26 26      // NPAD2 / 128
#define KC 288       // correlation K = C2*9

typedef __bf16 bf16x8 __attribute__((ext_vector_type(8)));
typedef float  f32x4  __attribute__((ext_vector_type(4)));

__device__ __constant__ int SC_SIZE[5] = {32, 28, 25, 22, 19};
__device__ __constant__ int SC_OFF[6]  = {0, 1024, 1808, 2433, 2917, 3278};

// ---------------- stage A: match_base = PReLU(conv1x1(x, w_base)); og splits channels ----------------
__global__ void k_match_base(const float* __restrict__ x, const float* __restrict__ w,
                             const float* __restrict__ bias, const float* __restrict__ a,
                             float* __restrict__ mb) {
    int t = blockIdx.x * blockDim.x + threadIdx.x;   // [0, B*HW)
    int o0 = blockIdx.y * 8;                         // 4 channel groups of 8
    int b = t >> 10, p = t & 1023;
    float alpha = a[0];
    float xv[CC];
    const float* xb = x + (size_t)b * CC * HW + p;
#pragma unroll
    for (int c = 0; c < CC; ++c) xv[c] = xb[c * HW];
#pragma unroll
    for (int oi = 0; oi < 8; ++oi) {
        int o = o0 + oi;
        float acc = bias[o];
#pragma unroll
        for (int c = 0; c < CC; ++c) acc += w[o * CC + c] * xv[c];
        mb[((size_t)b * C2 + o) * HW + p] = acc >= 0.f ? acc : alpha * acc;
    }
}

// ---------------- stage B: per-scale refm (fp32) / base (bf16); og splits channels ----------------
__global__ void k_scale_feats(const float* __restrict__ x,
                              const float* __restrict__ wm, const float* __restrict__ bm, const float* __restrict__ am,
                              const float* __restrict__ wa, const float* __restrict__ ba, const float* __restrict__ aa,
                              float* __restrict__ refm, __bf16* __restrict__ base) {
    int t = blockIdx.x * blockDim.x + threadIdx.x;
    if (t >= BB * NTOT) return;
    int og = blockIdx.y;     // 0..3 -> asm ch og*16; 4..5 -> match ch (og-4)*16
    int b = t / NTOT, n = t % NTOT;
    int s = 0;
    while (s < 4 && n >= SC_OFF[s + 1]) ++s;
    int q = n - SC_OFF[s];
    int hs = SC_SIZE[s];
    int ny = q / hs, nx = q % hs;
    int iy = (ny * HH) / hs, ix = (nx * WW) / hs;
    const float* xb = x + (size_t)b * CC * HW + iy * WW + ix;
    float xv[CC];
#pragma unroll
    for (int c = 0; c < CC; ++c) xv[c] = xb[c * HW];
    if (og < 4) {
        float ala = aa[0];
        int o0 = og * 16;
#pragma unroll
        for (int oi = 0; oi < 16; ++oi) {
            int o = o0 + oi;
            float acc = ba[o];
#pragma unroll
            for (int c = 0; c < CC; ++c) acc += wa[o * CC + c] * xv[c];
            base[((size_t)b * CC + o) * NTOT + n] = (__bf16)(acc >= 0.f ? acc : ala * acc);
        }
    } else {
        float alm = am[0];
        int o0 = (og - 4) * 16;
#pragma unroll
        for (int oi = 0; oi < 16; ++oi) {
            int o = o0 + oi;
            float acc = bm[o];
#pragma unroll
            for (int c = 0; c < CC; ++c) acc += wm[o * CC + c] * xv[c];
            refm[((size_t)b * C2 + o) * NTOT + n] = acc >= 0.f ? acc : alm * acc;
        }
    }
}

// ---------------- neighbor table ----------------
__global__ void k_nbr(int* __restrict__ nbr) {
    int n = blockIdx.x * blockDim.x + threadIdx.x;
    if (n >= NTOT) return;
    int s = 0;
    while (s < 4 && n >= SC_OFF[s + 1]) ++s;
    int q = n - SC_OFF[s];
    int hs = SC_SIZE[s];
    int ny = q / hs, nx = q % hs;
    for (int dy = 0; dy < 3; ++dy)
        for (int dx = 0; dx < 3; ++dx) {
            int yy = ny + dy - 1, xx = nx + dx - 1;
            int idx = (yy >= 0 && yy < hs && xx >= 0 && xx < hs) ? (SC_OFF[s] + yy * hs + xx) : -1;
            nbr[(dy * 3 + dx) * NTOT + n] = idx;
        }
}

// ---------------- per-(b,n) filter norms; sinv = 10 / max(norm, 1e-4) ----------------
__global__ void k_norms(const float* __restrict__ refm, const int* __restrict__ nbr,
                        float* __restrict__ sinv) {
    int t = blockIdx.x * blockDim.x + threadIdx.x;
    if (t >= BB * NTOT) return;
    int b = t / NTOT, n = t % NTOT;
    float sum = 0.f;
    for (int kk = 0; kk < 9; ++kk) {
        int idx = nbr[kk * NTOT + n];
        if (idx < 0) continue;
        const float* r = refm + (size_t)b * C2 * NTOT + idx;
#pragma unroll
        for (int c = 0; c < C2; ++c) {
            float v = r[(size_t)c * NTOT];
            sum += v * v;
        }
    }
    sinv[t] = 10.0f / fmaxf(sqrtf(sum), 1e-4f);
}

// ---------------- xpat gather: match_base patches -> [cb][p][KC] bf16 hi/lo ----------------
__global__ void k_xpat(const float* __restrict__ mb, __bf16* __restrict__ xh,
                       __bf16* __restrict__ xl, int b0) {
    int t = blockIdx.x * 256 + threadIdx.x;   // over HW*KC
    int cb = blockIdx.y;
    int p = t / KC, k = t % KC;
    int c2 = k / 9, kk = k % 9;
    int py = (p >> 5) + kk / 3 - 1;
    int px = (p & 31) + kk % 3 - 1;
    float v = 0.f;
    if (py >= 0 && py < HH && px >= 0 && px < WW)
        v = mb[((size_t)(b0 + cb) * C2 + c2) * HW + py * WW + px];
    __bf16 hi = (__bf16)v;
    size_t o = ((size_t)cb * HW + p) * KC + k;
    xh[o] = hi;
    xl[o] = (__bf16)(v - (float)hi);
}

// ---------------- wib gather: wi rows -> [cb][n][KC] bf16 hi/lo (zero-padded n) ----------------
__global__ void k_wib(const float* __restrict__ refm, const int* __restrict__ nbr,
                      __bf16* __restrict__ wh, __bf16* __restrict__ wl, int b0) {
    int t = blockIdx.x * 256 + threadIdx.x;   // over NPAD2*KC
    int cb = blockIdx.y;
    int n = t / KC, k = t % KC;
    int c2 = k / 9, kk = k % 9;
    float v = 0.f;
    if (n < NTOT) {
        int idx = nbr[kk * NTOT + n];
        if (idx >= 0) v = refm[((size_t)(b0 + cb) * C2 + c2) * NTOT + idx];
    }
    __bf16 hi = (__bf16)v;
    size_t o = ((size_t)cb * NPAD2 + n) * KC + k;
    wh[o] = hi;
    wl[o] = (__bf16)(v - (float)hi);
}

// ---------------- correlation GEMM (MFMA, split-bf16) + fused partial softmax ----------------
// tile M=64(p) x N=128(n); writes t = exp(v - M_blk) bf16 and per-(p,ntile) partials (M_blk, S_blk)
__global__ void k_corr_mfma(const __bf16* __restrict__ xh, const __bf16* __restrict__ xl,
                            const __bf16* __restrict__ wh, const __bf16* __restrict__ wl,
                            const float* __restrict__ sinv, __bf16* __restrict__ tbuf,
                            float* __restrict__ partM, float* __restrict__ partS, int b0) {
    int ptile = blockIdx.x;   // 16 tiles of 64 p
    int ntile = blockIdx.y;   // 26 tiles of 128 n
    int cb    = blockIdx.z;
    int tid  = threadIdx.x;
    int lane = tid & 63, wave = tid >> 6;
    int row16 = lane & 15, quad = lane >> 4;

    __shared__ __bf16 Ah[64 * 40], Al[64 * 40];
    __shared__ __bf16 Bh[128 * 40], Bl[128 * 40];
    __shared__ float redM[4][64], redS[4][64];

    const __bf16* Aph = xh + ((size_t)cb * HW + ptile * 64) * KC;
    const __bf16* Apl = xl + ((size_t)cb * HW + ptile * 64) * KC;
    const __bf16* Bph = wh + ((size_t)cb * NPAD2 + ntile * 128) * KC;
    const __bf16* Bpl = wl + ((size_t)cb * NPAD2 + ntile * 128) * KC;

    f32x4 acc[4][2];
#pragma unroll
    for (int i = 0; i < 4; ++i)
#pragma unroll
        for (int j = 0; j < 2; ++j) acc[i][j] = (f32x4){0.f, 0.f, 0.f, 0.f};

    int lr = tid >> 2, lk = (tid & 3) * 8;
    for (int k0 = 0; k0 < KC; k0 += 32) {
        *(bf16x8*)&Ah[lr * 40 + lk] = *(const bf16x8*)(Aph + (size_t)lr * KC + k0 + lk);
        *(bf16x8*)&Al[lr * 40 + lk] = *(const bf16x8*)(Apl + (size_t)lr * KC + k0 + lk);
#pragma unroll
        for (int i = 0; i < 2; ++i) {
            int r = tid + i * 256;
            int rr = r >> 2, rk = (r & 3) * 8;
            *(bf16x8*)&Bh[rr * 40 + rk] = *(const bf16x8*)(Bph + (size_t)rr * KC + k0 + rk);
            *(bf16x8*)&Bl[rr * 40 + rk] = *(const bf16x8*)(Bpl + (size_t)rr * KC + k0 + rk);
        }
        __syncthreads();
        bf16x8 ah[4], al[4], bh[2], bl[2];
#pragma unroll
        for (int m = 0; m < 4; ++m) {
            ah[m] = *(const bf16x8*)&Ah[(m * 16 + row16) * 40 + quad * 8];
            al[m] = *(const bf16x8*)&Al[(m * 16 + row16) * 40 + quad * 8];
        }
#pragma unroll
        for (int nb = 0; nb < 2; ++nb) {
            bh[nb] = *(const bf16x8*)&Bh[(wave * 32 + nb * 16 + row16) * 40 + quad * 8];
            bl[nb] = *(const bf16x8*)&Bl[(wave * 32 + nb * 16 + row16) * 40 + quad * 8];
        }
#pragma unroll
        for (int m = 0; m < 4; ++m)
#pragma unroll
            for (int nb = 0; nb < 2; ++nb) {
                acc[m][nb] = __builtin_amdgcn_mfma_f32_16x16x32_bf16(ah[m], bh[nb], acc[m][nb], 0, 0, 0);
                acc[m][nb] = __builtin_amdgcn_mfma_f32_16x16x32_bf16(ah[m], bl[nb], acc[m][nb], 0, 0, 0);
                acc[m][nb] = __builtin_amdgcn_mfma_f32_16x16x32_bf16(al[m], bh[nb], acc[m][nb], 0, 0, 0);
            }
        __syncthreads();
    }

    // ---- fused epilogue: scale by sinv, per-row block max/sumexp, write t = exp(v - M_blk) ----
    int nn[2];
    float sv[2];
    bool valid[2];
#pragma unroll
    for (int nb = 0; nb < 2; ++nb) {
        nn[nb] = ntile * 128 + wave * 32 + nb * 16 + row16;
        valid[nb] = nn[nb] < NTOT;
        sv[nb] = valid[nb] ? sinv[(size_t)(b0 + cb) * NTOT + nn[nb]] : 0.f;
    }
#pragma unroll
    for (int m = 0; m < 4; ++m)
#pragma unroll
        for (int nb = 0; nb < 2; ++nb)
#pragma unroll
            for (int r = 0; r < 4; ++r) acc[m][nb][r] *= sv[nb];

    float mx[4][4];
#pragma unroll
    for (int m = 0; m < 4; ++m)
#pragma unroll
        for (int r = 0; r < 4; ++r)
            mx[m][r] = fmaxf(valid[0] ? acc[m][0][r] : -1e30f,
                             valid[1] ? acc[m][1][r] : -1e30f);
#pragma unroll
    for (int msk = 1; msk < 16; msk <<= 1)
#pragma unroll
        for (int m = 0; m < 4; ++m)
#pragma unroll
            for (int r = 0; r < 4; ++r)
                mx[m][r] = fmaxf(mx[m][r], __shfl_xor(mx[m][r], msk, 64));
    if (row16 == 0)
#pragma unroll
        for (int m = 0; m < 4; ++m)
#pragma unroll
            for (int r = 0; r < 4; ++r) redM[wave][m * 16 + quad * 4 + r] = mx[m][r];
    __syncthreads();
    float Mr[4][4];
#pragma unroll
    for (int m = 0; m < 4; ++m)
#pragma unroll
        for (int r = 0; r < 4; ++r) {
            int p = m * 16 + quad * 4 + r;
            Mr[m][r] = fmaxf(fmaxf(redM[0][p], redM[1][p]), fmaxf(redM[2][p], redM[3][p]));
        }
    float sm[4][4] = {};
#pragma unroll
    for (int m = 0; m < 4; ++m)
#pragma unroll
        for (int nb = 0; nb < 2; ++nb) {
            size_t rb = ((size_t)cb * HW + ptile * 64 + m * 16) * NPAD2 + nn[nb];
#pragma unroll
            for (int r = 0; r < 4; ++r) {
                float e = valid[nb] ? __expf(acc[m][nb][r] - Mr[m][r]) : 0.f;
                tbuf[rb + (size_t)(quad * 4 + r) * NPAD2] = (__bf16)e;
                sm[m][r] += e;
            }
        }
#pragma unroll
    for (int msk = 1; msk < 16; msk <<= 1)
#pragma unroll
        for (int m = 0; m < 4; ++m)
#pragma unroll
            for (int r = 0; r < 4; ++r) sm[m][r] += __shfl_xor(sm[m][r], msk, 64);
    if (row16 == 0)
#pragma unroll
        for (int m = 0; m < 4; ++m)
#pragma unroll
            for (int r = 0; r < 4; ++r) redS[wave][m * 16 + quad * 4 + r] = sm[m][r];
    __syncthreads();
    if (wave == 0 && row16 == 0) {
#pragma unroll
        for (int m = 0; m < 4; ++m)
#pragma unroll
            for (int r = 0; r < 4; ++r) {
                int p = m * 16 + quad * 4 + r;
                float S = redS[0][p] + redS[1][p] + redS[2][p] + redS[3][p];
                size_t o = ((size_t)cb * HW + ptile * 64 + p) * NT26 + ntile;
                partM[o] = Mr[m][r];
                partS[o] = S;
            }
    }
}

// ---------------- softmax finalize: reduce 26 partials per row; scale t in place ----------------
__global__ void k_softmax_fin(__bf16* __restrict__ t, const float* __restrict__ pM,
                              const float* __restrict__ pS) {
    int row = blockIdx.x;   // cb*HW + p
    __shared__ float alpha[NT26];
    int tid = threadIdx.x;
    if (tid < 64) {
        float m = (tid < NT26) ? pM[(size_t)row * NT26 + tid] : -1e30f;
        float s = (tid < NT26) ? pS[(size_t)row * NT26 + tid] : 0.f;
        float M = m;
#pragma unroll
        for (int msk = 1; msk < 64; msk <<= 1) M = fmaxf(M, __shfl_xor(M, msk, 64));
        float e = __expf(m - M);
        float se = s * e;
#pragma unroll
        for (int msk = 1; msk < 64; msk <<= 1) se += __shfl_xor(se, msk, 64);
        if (tid < NT26) alpha[tid] = e / se;
    }
    __syncthreads();
    for (int i = tid; i < NPAD2 / 8; i += 256) {
        bf16x8* ptr = (bf16x8*)&t[(size_t)row * NPAD2 + i * 8];
        bf16x8 v = *ptr;
        float a = alpha[i >> 4];
#pragma unroll
        for (int j = 0; j < 8; ++j) v[j] = (__bf16)((float)v[j] * a);
        *ptr = v;
    }
}

// ---------------- V gather: Vb[cb][m=576][NPAD2] bf16 ----------------
__global__ void k_vgather(const __bf16* __restrict__ base, const int* __restrict__ nbr,
                          __bf16* __restrict__ Vb, int b0) {
    int n = blockIdx.x * 256 + threadIdx.x;
    int m = blockIdx.y;
    int cb = blockIdx.z;
    int c = m / 9, kk = m % 9;
    __bf16 v = (__bf16)0.f;
    if (n < NTOT) {
        int idx = nbr[kk * NTOT + n];
        if (idx >= 0) v = base[((size_t)(b0 + cb) * CC + c) * NTOT + idx];
    }
    Vb[((size_t)cb * 576 + m) * NPAD2 + n] = v;
}

// ---------------- fold GEMM (MFMA bf16): outacc[cb][m][p] = sum_n V[m,n]*prob[p,n] ----------------
__global__ void k_fold_mfma(const __bf16* __restrict__ Vb, const __bf16* __restrict__ prob,
                            float* __restrict__ outacc) {
    int ptile = blockIdx.x;   // 8 tiles of 128 p
    int mtile = blockIdx.y;   // 9 tiles of 64 m
    int cb    = blockIdx.z;
    int tid  = threadIdx.x;
    int lane = tid & 63, wave = tid >> 6;
    int row16 = lane & 15, quad = lane >> 4;

    __shared__ __bf16 Als[64 * 40];
    __shared__ __bf16 Bls[128 * 40];

    const __bf16* Vp = Vb   + (size_t)cb * 576 * NPAD2 + (size_t)mtile * 64 * NPAD2;
    const __bf16* Pp = prob + (size_t)cb * HW  * NPAD2 + (size_t)ptile * 128 * NPAD2;

    f32x4 acc[4][2];
#pragma unroll
    for (int i = 0; i < 4; ++i)
#pragma unroll
        for (int j = 0; j < 2; ++j) acc[i][j] = (f32x4){0.f, 0.f, 0.f, 0.f};

    int lm = tid >> 2, lkq = (tid & 3) * 8;
    for (int k0 = 0; k0 < NPAD2; k0 += 32) {
        *(bf16x8*)&Als[lm * 40 + lkq] = *(const bf16x8*)(Vp + (size_t)lm * NPAD2 + k0 + lkq);
#pragma unroll
        for (int i = 0; i < 2; ++i) {
            int r = tid + i * 256;
            int p = r >> 2, kq = (r & 3) * 8;
            *(bf16x8*)&Bls[p * 40 + kq] = *(const bf16x8*)(Pp + (size_t)p * NPAD2 + k0 + kq);
        }
        __syncthreads();
        bf16x8 af[4], bf[2];
#pragma unroll
        for (int mb = 0; mb < 4; ++mb)
            af[mb] = *(const bf16x8*)&Als[(mb * 16 + row16) * 40 + quad * 8];
#pragma unroll
        for (int pb = 0; pb < 2; ++pb)
            bf[pb] = *(const bf16x8*)&Bls[(wave * 32 + pb * 16 + row16) * 40 + quad * 8];
#pragma unroll
        for (int mb = 0; mb < 4; ++mb)
#pragma unroll
            for (int pb = 0; pb < 2; ++pb)
                acc[mb][pb] = __builtin_amdgcn_mfma_f32_16x16x32_bf16(af[mb], bf[pb], acc[mb][pb], 0, 0, 0);
        __syncthreads();
    }
#pragma unroll
    for (int mb = 0; mb < 4; ++mb)
#pragma unroll
        for (int pb = 0; pb < 2; ++pb) {
#pragma unroll
            for (int r = 0; r < 4; ++r) {
                int mg = mtile * 64 + mb * 16 + quad * 4 + r;
                int pg = ptile * 128 + wave * 32 + pb * 16 + row16;
                outacc[((size_t)cb * 576 + mg) * HW + pg] = acc[mb][pb][r];
            }
        }
}

// ---------------- epilogue ----------------
__global__ void k_epilogue(const float* __restrict__ x, const float* __restrict__ outacc,
                           float* __restrict__ out, int b0) {
    int t = blockIdx.x * blockDim.x + threadIdx.x;
    int cb = t >> 16;
    int c = (t >> 10) & 63;
    int p = t & 1023;
    int b = b0 + cb;
    int y = p >> 5, xx = p & 31;
    float acc = 0.f;
#pragma unroll
    for (int ky = 0; ky < 3; ++ky)
#pragma unroll
        for (int kx = 0; kx < 3; ++kx) {
            int py = y + 1 - ky, px = xx + 1 - kx;
            if (py >= 0 && py < HH && px >= 0 && px < WW)
                acc += outacc[((size_t)cb * 576 + c * 9 + ky * 3 + kx) * HW + py * WW + px];
        }
    size_t o = ((size_t)b * CC + c) * HW + p;
    out[o] = x[o] + 0.25f * acc;
}

extern "C" void kernel_launch(void* const* d_in, const int* in_sizes, int n_in,
                              void* d_out, int out_size, void* d_ws, size_t ws_size,
                              hipStream_t stream) {
    const float* x       = (const float*)d_in[0];
    const float* w_base  = (const float*)d_in[1];
    const float* b_base  = (const float*)d_in[2];
    const float* a_base  = (const float*)d_in[3];
    const float* w_match = (const float*)d_in[4];
    const float* b_match = (const float*)d_in[5];
    const float* a_match = (const float*)d_in[6];
    const float* w_asm   = (const float*)d_in[7];
    const float* b_asm   = (const float*)d_in[8];
    const float* a_asm   = (const float*)d_in[9];
    float* out = (float*)d_out;

    // ---- pick chunk size CB by workspace ----
    const size_t fixed = ((size_t)BB * C2 * HW * 4) + ((size_t)BB * C2 * NTOT * 4) +
                         ((size_t)BB * CC * NTOT * 2) + ((size_t)BB * NTOT * 4) +
                         ((size_t)9 * NTOT * 4) + 4096;
    const size_t perCB = ((size_t)HW * KC * 2 * 2) + ((size_t)NPAD2 * KC * 2 * 2) +
                         ((size_t)HW * NPAD2 * 2) + ((size_t)HW * NT26 * 4 * 2) +
                         ((size_t)576 * NPAD2 * 2) + ((size_t)576 * HW * 4) + 4096;
    int CB = 8;
    while (CB > 1 && fixed + perCB * CB > ws_size) CB >>= 1;

    char* ws = (char*)d_ws;
    size_t off = 0;
    auto alloc_b = [&](size_t bytes) {
        void* p = (void*)(ws + off);
        off += bytes;
        off = (off + 255) & ~(size_t)255;
        return p;
    };
    float*  mb      = (float*)alloc_b((size_t)BB * C2 * HW * 4);
    float*  refm    = (float*)alloc_b((size_t)BB * C2 * NTOT * 4);
    __bf16* base_bf = (__bf16*)alloc_b((size_t)BB * CC * NTOT * 2);
    float*  sinv    = (float*)alloc_b((size_t)BB * NTOT * 4);
    int*    nbr     = (int*)alloc_b((size_t)9 * NTOT * 4);
    __bf16* xpat_h  = (__bf16*)alloc_b((size_t)CB * HW * KC * 2);
    __bf16* xpat_l  = (__bf16*)alloc_b((size_t)CB * HW * KC * 2);
    __bf16* wib_h   = (__bf16*)alloc_b((size_t)CB * NPAD2 * KC * 2);
    __bf16* wib_l   = (__bf16*)alloc_b((size_t)CB * NPAD2 * KC * 2);
    __bf16* tbuf    = (__bf16*)alloc_b((size_t)CB * HW * NPAD2 * 2);
    float*  partM   = (float*)alloc_b((size_t)CB * HW * NT26 * 4);
    float*  partS   = (float*)alloc_b((size_t)CB * HW * NT26 * 4);
    __bf16* Vb      = (__bf16*)alloc_b((size_t)CB * 576 * NPAD2 * 2);
    float*  outacc  = (float*)alloc_b((size_t)CB * 576 * HW * 4);
    if (off > ws_size) return;  // should not happen given CB selection

    k_match_base<<<dim3(BB * HW / 256, 4), 256, 0, stream>>>(x, w_base, b_base, a_base, mb);
    k_scale_feats<<<dim3((BB * NTOT + 255) / 256, 6), 256, 0, stream>>>(
        x, w_match, b_match, a_match, w_asm, b_asm, a_asm, refm, base_bf);
    k_nbr<<<(NTOT + 255) / 256, 256, 0, stream>>>(nbr);
    k_norms<<<(BB * NTOT + 255) / 256, 256, 0, stream>>>(refm, nbr, sinv);

    for (int b0 = 0; b0 < BB; b0 += CB) {
        k_xpat<<<dim3(HW * KC / 256, CB), 256, 0, stream>>>(mb, xpat_h, xpat_l, b0);
        k_wib<<<dim3(NPAD2 * KC / 256, CB), 256, 0, stream>>>(refm, nbr, wib_h, wib_l, b0);
        k_corr_mfma<<<dim3(16, NT26, CB), 256, 0, stream>>>(
            xpat_h, xpat_l, wib_h, wib_l, sinv, tbuf, partM, partS, b0);
        k_softmax_fin<<<CB * HW, 256, 0, stream>>>(tbuf, partM, partS);
        k_vgather<<<dim3(NPAD2 / 256, 576, CB), 256, 0, stream>>>(base_bf, nbr, Vb, b0);
        k_fold_mfma<<<dim3(8, 9, CB), 256, 0, stream>>>(Vb, tbuf, outacc);
        k_epilogue<<<CB * CC * HW / 256, 256, 0, stream>>>(x, outacc, out, b0);
    }
}

// Round 5
// 1088.712 us; speedup vs baseline: 6.7010x; 1.1432x over previous
//
#include <hip/hip_runtime.h>
#include <hip/hip_bf16.h>
#include <math.h>

#define BB 32
#define CC 64
#define C2 32
#define HH 32
#define WW 32
#define HW 1024
#define NTOT 3278
#define NPAD2 3328   // padded N (multiple of 128) for MFMA corr + fold
#define NT26 26      // NPAD2 / 128
#define KC 288       // correlation K = C2*9

typedef __bf16 bf16x8 __attribute__((ext_vector_type(8)));
typedef float  f32x4  __attribute__((ext_vector_type(4)));

__device__ __constant__ int SC_SIZE[5] = {32, 28, 25, 22, 19};
__device__ __constant__ int SC_OFF[6]  = {0, 1024, 1808, 2433, 2917, 3278};

// ---------------- fused feature kernel: all convs on the full 32x32 grid ----------------
// og=0: mb (w_base,32ch fp32) + rm_full (w_match,32ch fp32) + per-pixel sumsq of each
// og=1: base_full (w_asm,64ch bf16)
__global__ void k_feats(const float* __restrict__ x,
                        const float* __restrict__ wb, const float* __restrict__ bb, const float* __restrict__ ab,
                        const float* __restrict__ wm, const float* __restrict__ bm, const float* __restrict__ am,
                        const float* __restrict__ wa, const float* __restrict__ ba, const float* __restrict__ aa,
                        float* __restrict__ mb, float* __restrict__ rmf, __bf16* __restrict__ basef,
                        float* __restrict__ mbss, float* __restrict__ rmss) {
    int og = blockIdx.y;
    __shared__ float wsm[4096];
    __shared__ float bsh[64];
    int tid = threadIdx.x;
    if (og == 0) {
        for (int i = tid; i < 2048; i += 256) wsm[i] = wb[i];
        for (int i = tid; i < 2048; i += 256) wsm[2048 + i] = wm[i];
        if (tid < 32) bsh[tid] = bb[tid];
        else if (tid < 64) bsh[tid] = bm[tid - 32];
    } else {
        for (int i = tid; i < 4096; i += 256) wsm[i] = wa[i];
        if (tid < 64) bsh[tid] = ba[tid];
    }
    __syncthreads();
    int t = blockIdx.x * 256 + tid;
    int b = t >> 10, p = t & 1023;
    float xv[CC];
    const float* xb = x + (size_t)b * CC * HW + p;
#pragma unroll
    for (int c = 0; c < CC; ++c) xv[c] = xb[c * HW];
    if (og == 0) {
        float alb = ab[0], alm = am[0];
        float sb = 0.f, sm = 0.f;
        for (int o = 0; o < C2; ++o) {
            float acc = bsh[o];
#pragma unroll
            for (int c = 0; c < CC; ++c) acc += wsm[o * CC + c] * xv[c];
            float v = acc >= 0.f ? acc : alb * acc;
            mb[((size_t)b * C2 + o) * HW + p] = v;
            sb += v * v;
        }
        for (int o = 0; o < C2; ++o) {
            float acc = bsh[32 + o];
#pragma unroll
            for (int c = 0; c < CC; ++c) acc += wsm[2048 + o * CC + c] * xv[c];
            float v = acc >= 0.f ? acc : alm * acc;
            rmf[((size_t)b * C2 + o) * HW + p] = v;
            sm += v * v;
        }
        mbss[t] = sb;
        rmss[t] = sm;
    } else {
        float ala = aa[0];
        for (int o = 0; o < CC; ++o) {
            float acc = bsh[o];
#pragma unroll
            for (int c = 0; c < CC; ++c) acc += wsm[o * CC + c] * xv[c];
            float v = acc >= 0.f ? acc : ala * acc;
            basef[((size_t)b * CC + o) * HW + p] = (__bf16)v;
        }
    }
}

// ---------------- neighbor table: full-grid position of tap kk at concat-index n, or -1 ----------------
__global__ void k_nbr(int* __restrict__ nbr_pos) {
    int n = blockIdx.x * blockDim.x + threadIdx.x;
    if (n >= NTOT) return;
    int s = 0;
    while (s < 4 && n >= SC_OFF[s + 1]) ++s;
    int q = n - SC_OFF[s];
    int hs = SC_SIZE[s];
    int ny = q / hs, nx = q % hs;
    for (int dy = 0; dy < 3; ++dy)
        for (int dx = 0; dx < 3; ++dx) {
            int yy = ny + dy - 1, xx = nx + dx - 1;
            int pos = -1;
            if (yy >= 0 && yy < hs && xx >= 0 && xx < hs)
                pos = ((yy * HH) / hs) * WW + (xx * WW) / hs;
            nbr_pos[(dy * 3 + dx) * NTOT + n] = pos;
        }
}

// ---------------- per-(b,p) logit upper bound: Mub = 10*||xp[p]|| from mbss 9-tap ----------------
__global__ void k_qnorm(const float* __restrict__ mbss, float* __restrict__ qub) {
    int t = blockIdx.x * blockDim.x + threadIdx.x;   // [0, BB*HW)
    int b = t >> 10, p = t & 1023;
    int y = p >> 5, x = p & 31;
    float s = 0.f;
#pragma unroll
    for (int dy = 0; dy < 3; ++dy)
#pragma unroll
        for (int dx = 0; dx < 3; ++dx) {
            int yy = y + dy - 1, xx = x + dx - 1;
            if (yy >= 0 && yy < HH && xx >= 0 && xx < WW)
                s += mbss[(size_t)b * HW + yy * WW + xx];
        }
    qub[t] = 10.0f * sqrtf(s);
}

// ---------------- per-(b,n) filter norms from rmss 9-tap; sinv = 10/max(norm,1e-4) ----------------
__global__ void k_norms(const float* __restrict__ rmss, const int* __restrict__ nbr_pos,
                        float* __restrict__ sinv) {
    int t = blockIdx.x * blockDim.x + threadIdx.x;
    if (t >= BB * NTOT) return;
    int b = t / NTOT, n = t % NTOT;
    float sum = 0.f;
#pragma unroll
    for (int kk = 0; kk < 9; ++kk) {
        int pos = nbr_pos[kk * NTOT + n];
        if (pos >= 0) sum += rmss[(size_t)b * HW + pos];
    }
    sinv[t] = 10.0f / fmaxf(sqrtf(sum), 1e-4f);
}

// ---------------- xpat gather: mb patches -> [cb][p][KC] bf16 hi/lo ----------------
__global__ void k_xpat(const float* __restrict__ mb, __bf16* __restrict__ xh,
                       __bf16* __restrict__ xl, int b0) {
    int t = blockIdx.x * 256 + threadIdx.x;   // over HW*KC
    int cb = blockIdx.y;
    int p = t / KC, k = t % KC;
    int c2 = k / 9, kk = k % 9;
    int py = (p >> 5) + kk / 3 - 1;
    int px = (p & 31) + kk % 3 - 1;
    float v = 0.f;
    if (py >= 0 && py < HH && px >= 0 && px < WW)
        v = mb[((size_t)(b0 + cb) * C2 + c2) * HW + py * WW + px];
    __bf16 hi = (__bf16)v;
    size_t o = ((size_t)cb * HW + p) * KC + k;
    xh[o] = hi;
    xl[o] = (__bf16)(v - (float)hi);
}

// ---------------- wib gather: wi rows from rm_full -> [cb][n][KC] bf16 hi/lo ----------------
__global__ void k_wib(const float* __restrict__ rmf, const int* __restrict__ nbr_pos,
                      __bf16* __restrict__ wh, __bf16* __restrict__ wl, int b0) {
    int t = blockIdx.x * 256 + threadIdx.x;   // over NPAD2*KC
    int cb = blockIdx.y;
    int n = t / KC, k = t % KC;
    int c2 = k / 9, kk = k % 9;
    float v = 0.f;
    if (n < NTOT) {
        int pos = nbr_pos[kk * NTOT + n];
        if (pos >= 0) v = rmf[((size_t)(b0 + cb) * C2 + c2) * HW + pos];
    }
    __bf16 hi = (__bf16)v;
    size_t o = ((size_t)cb * NPAD2 + n) * KC + k;
    wh[o] = hi;
    wl[o] = (__bf16)(v - (float)hi);
}

// ---------------- correlation GEMM (MFMA, split-bf16) + t = exp(v - Mub[p]) epilogue ----------------
__global__ void k_corr_mfma(const __bf16* __restrict__ xh, const __bf16* __restrict__ xl,
                            const __bf16* __restrict__ wh, const __bf16* __restrict__ wl,
                            const float* __restrict__ sinv, const float* __restrict__ qub,
                            __bf16* __restrict__ tbuf, float* __restrict__ partS, int b0) {
    int ptile = blockIdx.x;   // 16 tiles of 64 p
    int ntile = blockIdx.y;   // 26 tiles of 128 n
    int cb    = blockIdx.z;
    int tid  = threadIdx.x;
    int lane = tid & 63, wave = tid >> 6;
    int row16 = lane & 15, quad = lane >> 4;

    __shared__ __bf16 Ah[64 * 40], Al[64 * 40];
    __shared__ __bf16 Bh[128 * 40], Bl[128 * 40];
    __shared__ float sMub[64];
    __shared__ float redS[4][64];

    if (tid < 64) sMub[tid] = qub[(size_t)(b0 + cb) * HW + ptile * 64 + tid];

    const __bf16* Aph = xh + ((size_t)cb * HW + ptile * 64) * KC;
    const __bf16* Apl = xl + ((size_t)cb * HW + ptile * 64) * KC;
    const __bf16* Bph = wh + ((size_t)cb * NPAD2 + ntile * 128) * KC;
    const __bf16* Bpl = wl + ((size_t)cb * NPAD2 + ntile * 128) * KC;

    f32x4 acc[4][2];
#pragma unroll
    for (int i = 0; i < 4; ++i)
#pragma unroll
        for (int j = 0; j < 2; ++j) acc[i][j] = (f32x4){0.f, 0.f, 0.f, 0.f};

    int lr = tid >> 2, lk = (tid & 3) * 8;
    for (int k0 = 0; k0 < KC; k0 += 32) {
        *(bf16x8*)&Ah[lr * 40 + lk] = *(const bf16x8*)(Aph + (size_t)lr * KC + k0 + lk);
        *(bf16x8*)&Al[lr * 40 + lk] = *(const bf16x8*)(Apl + (size_t)lr * KC + k0 + lk);
#pragma unroll
        for (int i = 0; i < 2; ++i) {
            int r = tid + i * 256;
            int rr = r >> 2, rk = (r & 3) * 8;
            *(bf16x8*)&Bh[rr * 40 + rk] = *(const bf16x8*)(Bph + (size_t)rr * KC + k0 + rk);
            *(bf16x8*)&Bl[rr * 40 + rk] = *(const bf16x8*)(Bpl + (size_t)rr * KC + k0 + rk);
        }
        __syncthreads();
        bf16x8 ah[4], al[4], bh[2], bl[2];
#pragma unroll
        for (int m = 0; m < 4; ++m) {
            ah[m] = *(const bf16x8*)&Ah[(m * 16 + row16) * 40 + quad * 8];
            al[m] = *(const bf16x8*)&Al[(m * 16 + row16) * 40 + quad * 8];
        }
#pragma unroll
        for (int nb = 0; nb < 2; ++nb) {
            bh[nb] = *(const bf16x8*)&Bh[(wave * 32 + nb * 16 + row16) * 40 + quad * 8];
            bl[nb] = *(const bf16x8*)&Bl[(wave * 32 + nb * 16 + row16) * 40 + quad * 8];
        }
#pragma unroll
        for (int m = 0; m < 4; ++m)
#pragma unroll
            for (int nb = 0; nb < 2; ++nb) {
                acc[m][nb] = __builtin_amdgcn_mfma_f32_16x16x32_bf16(ah[m], bh[nb], acc[m][nb], 0, 0, 0);
                acc[m][nb] = __builtin_amdgcn_mfma_f32_16x16x32_bf16(ah[m], bl[nb], acc[m][nb], 0, 0, 0);
                acc[m][nb] = __builtin_amdgcn_mfma_f32_16x16x32_bf16(al[m], bh[nb], acc[m][nb], 0, 0, 0);
            }
        __syncthreads();
    }

    // ---- epilogue: v = acc*sinv[n]; t = exp(v - Mub[p]); row-partial sums ----
    int nn[2];
    float sv[2];
    bool valid[2];
#pragma unroll
    for (int nb = 0; nb < 2; ++nb) {
        nn[nb] = ntile * 128 + wave * 32 + nb * 16 + row16;
        valid[nb] = nn[nb] < NTOT;
        sv[nb] = valid[nb] ? sinv[(size_t)(b0 + cb) * NTOT + nn[nb]] : 0.f;
    }
    float sm[4][4] = {};
#pragma unroll
    for (int m = 0; m < 4; ++m)
#pragma unroll
        for (int nb = 0; nb < 2; ++nb) {
            size_t rb = ((size_t)cb * HW + ptile * 64 + m * 16) * NPAD2 + nn[nb];
#pragma unroll
            for (int r = 0; r < 4; ++r) {
                float mub = sMub[m * 16 + quad * 4 + r];
                float e = valid[nb] ? __expf(acc[m][nb][r] * sv[nb] - mub) : 0.f;
                tbuf[rb + (size_t)(quad * 4 + r) * NPAD2] = (__bf16)e;
                sm[m][r] += e;
            }
        }
#pragma unroll
    for (int msk = 1; msk < 16; msk <<= 1)
#pragma unroll
        for (int m = 0; m < 4; ++m)
#pragma unroll
            for (int r = 0; r < 4; ++r) sm[m][r] += __shfl_xor(sm[m][r], msk, 64);
    if (row16 == 0)
#pragma unroll
        for (int m = 0; m < 4; ++m)
#pragma unroll
            for (int r = 0; r < 4; ++r) redS[wave][m * 16 + quad * 4 + r] = sm[m][r];
    __syncthreads();
    if (wave == 0 && row16 == 0) {
#pragma unroll
        for (int m = 0; m < 4; ++m)
#pragma unroll
            for (int r = 0; r < 4; ++r) {
                int p = m * 16 + quad * 4 + r;
                float S = redS[0][p] + redS[1][p] + redS[2][p] + redS[3][p];
                partS[((size_t)cb * HW + ptile * 64 + p) * NT26 + ntile] = S;
            }
    }
}

// ---------------- row sum reduce: fin[row] = 1 / sum_nt partS ----------------
__global__ void k_rowsum(const float* __restrict__ partS, float* __restrict__ fin) {
    int row = blockIdx.x * 256 + threadIdx.x;   // [0, CB*HW)
    float s = 0.f;
#pragma unroll
    for (int nt = 0; nt < NT26; ++nt) s += partS[(size_t)row * NT26 + nt];
    fin[row] = 1.0f / fmaxf(s, 1e-38f);
}

// ---------------- V gather: Vb[cb][m=576][NPAD2] bf16 from base_full ----------------
__global__ void k_vgather(const __bf16* __restrict__ basef, const int* __restrict__ nbr_pos,
                          __bf16* __restrict__ Vb, int b0) {
    int n = blockIdx.x * 256 + threadIdx.x;
    int m = blockIdx.y;
    int cb = blockIdx.z;
    int c = m / 9, kk = m % 9;
    __bf16 v = (__bf16)0.f;
    if (n < NTOT) {
        int pos = nbr_pos[kk * NTOT + n];
        if (pos >= 0) v = basef[((size_t)(b0 + cb) * CC + c) * HW + pos];
    }
    Vb[((size_t)cb * 576 + m) * NPAD2 + n] = v;
}

// ---------------- fold GEMM (MFMA bf16): outacc[cb][m][p] = (1/S[p]) * sum_n V[m,n]*t[p,n] ----------------
__global__ void k_fold_mfma(const __bf16* __restrict__ Vb, const __bf16* __restrict__ tbuf,
                            const float* __restrict__ fin, float* __restrict__ outacc) {
    int ptile = blockIdx.x;   // 8 tiles of 128 p
    int mtile = blockIdx.y;   // 9 tiles of 64 m
    int cb    = blockIdx.z;
    int tid  = threadIdx.x;
    int lane = tid & 63, wave = tid >> 6;
    int row16 = lane & 15, quad = lane >> 4;

    __shared__ __bf16 Als[64 * 40];
    __shared__ __bf16 Bls[128 * 40];

    const __bf16* Vp = Vb   + (size_t)cb * 576 * NPAD2 + (size_t)mtile * 64 * NPAD2;
    const __bf16* Pp = tbuf + (size_t)cb * HW  * NPAD2 + (size_t)ptile * 128 * NPAD2;

    f32x4 acc[4][2];
#pragma unroll
    for (int i = 0; i < 4; ++i)
#pragma unroll
        for (int j = 0; j < 2; ++j) acc[i][j] = (f32x4){0.f, 0.f, 0.f, 0.f};

    int lm = tid >> 2, lkq = (tid & 3) * 8;
    for (int k0 = 0; k0 < NPAD2; k0 += 32) {
        *(bf16x8*)&Als[lm * 40 + lkq] = *(const bf16x8*)(Vp + (size_t)lm * NPAD2 + k0 + lkq);
#pragma unroll
        for (int i = 0; i < 2; ++i) {
            int r = tid + i * 256;
            int p = r >> 2, kq = (r & 3) * 8;
            *(bf16x8*)&Bls[p * 40 + kq] = *(const bf16x8*)(Pp + (size_t)p * NPAD2 + k0 + kq);
        }
        __syncthreads();
        bf16x8 af[4], bf[2];
#pragma unroll
        for (int mb = 0; mb < 4; ++mb)
            af[mb] = *(const bf16x8*)&Als[(mb * 16 + row16) * 40 + quad * 8];
#pragma unroll
        for (int pb = 0; pb < 2; ++pb)
            bf[pb] = *(const bf16x8*)&Bls[(wave * 32 + pb * 16 + row16) * 40 + quad * 8];
#pragma unroll
        for (int mb = 0; mb < 4; ++mb)
#pragma unroll
            for (int pb = 0; pb < 2; ++pb)
                acc[mb][pb] = __builtin_amdgcn_mfma_f32_16x16x32_bf16(af[mb], bf[pb], acc[mb][pb], 0, 0, 0);
        __syncthreads();
    }
    float fsc[2];
#pragma unroll
    for (int pb = 0; pb < 2; ++pb)
        fsc[pb] = fin[(size_t)cb * HW + ptile * 128 + wave * 32 + pb * 16 + row16];
#pragma unroll
    for (int mb = 0; mb < 4; ++mb)
#pragma unroll
        for (int pb = 0; pb < 2; ++pb) {
#pragma unroll
            for (int r = 0; r < 4; ++r) {
                int mg = mtile * 64 + mb * 16 + quad * 4 + r;
                int pg = ptile * 128 + wave * 32 + pb * 16 + row16;
                outacc[((size_t)cb * 576 + mg) * HW + pg] = acc[mb][pb][r] * fsc[pb];
            }
        }
}

// ---------------- epilogue ----------------
__global__ void k_epilogue(const float* __restrict__ x, const float* __restrict__ outacc,
                           float* __restrict__ out, int b0) {
    int t = blockIdx.x * blockDim.x + threadIdx.x;
    int cb = t >> 16;
    int c = (t >> 10) & 63;
    int p = t & 1023;
    int b = b0 + cb;
    int y = p >> 5, xx = p & 31;
    float acc = 0.f;
#pragma unroll
    for (int ky = 0; ky < 3; ++ky)
#pragma unroll
        for (int kx = 0; kx < 3; ++kx) {
            int py = y + 1 - ky, px = xx + 1 - kx;
            if (py >= 0 && py < HH && px >= 0 && px < WW)
                acc += outacc[((size_t)cb * 576 + c * 9 + ky * 3 + kx) * HW + py * WW + px];
        }
    size_t o = ((size_t)b * CC + c) * HW + p;
    out[o] = x[o] + 0.25f * acc;
}

extern "C" void kernel_launch(void* const* d_in, const int* in_sizes, int n_in,
                              void* d_out, int out_size, void* d_ws, size_t ws_size,
                              hipStream_t stream) {
    const float* x       = (const float*)d_in[0];
    const float* w_base  = (const float*)d_in[1];
    const float* b_base  = (const float*)d_in[2];
    const float* a_base  = (const float*)d_in[3];
    const float* w_match = (const float*)d_in[4];
    const float* b_match = (const float*)d_in[5];
    const float* a_match = (const float*)d_in[6];
    const float* w_asm   = (const float*)d_in[7];
    const float* b_asm   = (const float*)d_in[8];
    const float* a_asm   = (const float*)d_in[9];
    float* out = (float*)d_out;

    // ---- pick chunk size CB by workspace ----
    const size_t fixed = ((size_t)BB * C2 * HW * 4) * 2 + ((size_t)BB * CC * HW * 2) +
                         ((size_t)BB * HW * 4) * 3 + ((size_t)BB * NTOT * 4) +
                         ((size_t)9 * NTOT * 4) + 65536;
    const size_t perCB = ((size_t)HW * KC * 2 * 2) + ((size_t)NPAD2 * KC * 2 * 2) +
                         ((size_t)HW * NPAD2 * 2) + ((size_t)HW * NT26 * 4) +
                         ((size_t)HW * 4) + ((size_t)576 * NPAD2 * 2) +
                         ((size_t)576 * HW * 4) + 65536;
    int CB = 16;
    while (CB > 1 && fixed + perCB * CB > ws_size) CB >>= 1;

    char* ws = (char*)d_ws;
    size_t off = 0;
    auto alloc_b = [&](size_t bytes) {
        void* p = (void*)(ws + off);
        off += bytes;
        off = (off + 255) & ~(size_t)255;
        return p;
    };
    float*  mb      = (float*)alloc_b((size_t)BB * C2 * HW * 4);     // 4.2 MB
    float*  rm_full = (float*)alloc_b((size_t)BB * C2 * HW * 4);     // 4.2 MB
    __bf16* base_f  = (__bf16*)alloc_b((size_t)BB * CC * HW * 2);    // 4.2 MB
    float*  mbss    = (float*)alloc_b((size_t)BB * HW * 4);
    float*  rmss    = (float*)alloc_b((size_t)BB * HW * 4);
    float*  qub     = (float*)alloc_b((size_t)BB * HW * 4);
    float*  sinv    = (float*)alloc_b((size_t)BB * NTOT * 4);
    int*    nbr_pos = (int*)alloc_b((size_t)9 * NTOT * 4);
    __bf16* xpat_h  = (__bf16*)alloc_b((size_t)CB * HW * KC * 2);
    __bf16* xpat_l  = (__bf16*)alloc_b((size_t)CB * HW * KC * 2);
    __bf16* wib_h   = (__bf16*)alloc_b((size_t)CB * NPAD2 * KC * 2);
    __bf16* wib_l   = (__bf16*)alloc_b((size_t)CB * NPAD2 * KC * 2);
    __bf16* tbuf    = (__bf16*)alloc_b((size_t)CB * HW * NPAD2 * 2);
    float*  partS   = (float*)alloc_b((size_t)CB * HW * NT26 * 4);
    float*  fin     = (float*)alloc_b((size_t)CB * HW * 4);
    __bf16* Vb      = (__bf16*)alloc_b((size_t)CB * 576 * NPAD2 * 2);
    float*  outacc  = (float*)alloc_b((size_t)CB * 576 * HW * 4);
    if (off > ws_size) return;

    k_feats<<<dim3(BB * HW / 256, 2), 256, 0, stream>>>(
        x, w_base, b_base, a_base, w_match, b_match, a_match, w_asm, b_asm, a_asm,
        mb, rm_full, base_f, mbss, rmss);
    k_nbr<<<(NTOT + 255) / 256, 256, 0, stream>>>(nbr_pos);
    k_qnorm<<<BB * HW / 256, 256, 0, stream>>>(mbss, qub);
    k_norms<<<(BB * NTOT + 255) / 256, 256, 0, stream>>>(rmss, nbr_pos, sinv);

    for (int b0 = 0; b0 < BB; b0 += CB) {
        k_xpat<<<dim3(HW * KC / 256, CB), 256, 0, stream>>>(mb, xpat_h, xpat_l, b0);
        k_wib<<<dim3(NPAD2 * KC / 256, CB), 256, 0, stream>>>(rm_full, nbr_pos, wib_h, wib_l, b0);
        k_corr_mfma<<<dim3(16, NT26, CB), 256, 0, stream>>>(
            xpat_h, xpat_l, wib_h, wib_l, sinv, qub, tbuf, partS, b0);
        k_rowsum<<<CB * HW / 256, 256, 0, stream>>>(partS, fin);
        k_vgather<<<dim3(NPAD2 / 256, 576, CB), 256, 0, stream>>>(base_f, nbr_pos, Vb, b0);
        k_fold_mfma<<<dim3(8, 9, CB), 256, 0, stream>>>(Vb, tbuf, fin, outacc);
        k_epilogue<<<CB * CC * HW / 256, 256, 0, stream>>>(x, outacc, out, b0);
    }
}